// Round 4
// baseline (2315.175 us; speedup 1.0000x reference)
//
#include <hip/hip_runtime.h>
#include <hip/hip_bf16.h>
#include <hip/hip_cooperative_groups.h>

// SARDecoder round 12: fused persistent step loop, CORRECT sync. r11's
// fence-free barrier raced (absmax 0.073 — stale h-state across XCDs).
// Retreat to the architecturally-guaranteed primitive: cooperative launch +
// cooperative_groups::this_grid().sync() (agent-scope release/acquire).
// h-state accesses remain agent-scope relaxed atomics (bypass L1/L2).
// Role bodies, hoisted VGPR weights, conv, workspace: identical to r11.

#define RNN   512
#define V1    111
#define STEPS 31
#define HWP   256
#define POOLF 11008
#define NWG   160

namespace cg = cooperative_groups;

typedef unsigned short ushortT;
typedef unsigned int   uintT;
typedef __attribute__((ext_vector_type(8))) short bf16x8;   // 8 bf16 (4 VGPRs)
typedef __attribute__((ext_vector_type(4))) float f32x4;

__device__ __forceinline__ float blo(uintT u){ union { uintT i; float f; } v; v.i = u << 16; return v.f; }
__device__ __forceinline__ float bhi(uintT u){ union { uintT i; float f; } v; v.i = u & 0xffff0000u; return v.f; }
__device__ __forceinline__ ushortT f2b(float f){
  __hip_bfloat16 h = __float2bfloat16(f);
  union { __hip_bfloat16 b; ushortT s; } v; v.b = h; return v.s;
}
__device__ __forceinline__ uintT packbf(float lo, float hi){
  return (uintT)f2b(lo) | ((uintT)f2b(hi) << 16);
}
__device__ __forceinline__ bf16x8 u4_to_b8(uint4 u){
  union { uint4 a; bf16x8 b; } v; v.a = u; return v.b;
}
__device__ __forceinline__ float sigf(float x){ return 1.f/(1.f + __expf(-x)); }
__device__ __forceinline__ float tanh_f(float x){ float e = __expf(2.f*x); return 1.f - 2.f/(e+1.f); }

__device__ __forceinline__ uintT aload_u(uintT* p){
  return __hip_atomic_load(p, __ATOMIC_RELAXED, __HIP_MEMORY_SCOPE_AGENT);
}
__device__ __forceinline__ float aload_f(float* p){
  return __hip_atomic_load(p, __ATOMIC_RELAXED, __HIP_MEMORY_SCOPE_AGENT);
}
__device__ __forceinline__ void astore_u(uintT* p, uintT v){
  __hip_atomic_store(p, v, __ATOMIC_RELAXED, __HIP_MEMORY_SCOPE_AGENT);
}
__device__ __forceinline__ void astore_f(float* p, float v){
  __hip_atomic_store(p, v, __ATOMIC_RELAXED, __HIP_MEMORY_SCOPE_AGENT);
}

// ---------------- init: zero states (98304 f32 = 384 KB) ----------------
__global__ __launch_bounds__(256) void k_init(float* __restrict__ p){
  p[blockIdx.x*256 + threadIdx.x] = 0.f;   // grid 384
}

// ---------------- featT: features fp32 [b][c][y][x] -> bf16 [b][yy0..9][xi0..33][c], zero halo ----------------
__global__ __launch_bounds__(256) void k_featT(const float* __restrict__ feat, uintT* __restrict__ fT){
  int idx = blockIdx.x*256 + threadIdx.x;   // 2,785,280 (grid 10880)
  int cp = idx & 255;
  int r  = idx >> 8;         // b*340 + yy*34 + xi
  int xi = r % 34;
  int q  = r / 34;
  int yy = q % 10;
  int b  = q / 10;
  float v0 = 0.f, v1 = 0.f;
  if (yy >= 1 && yy <= 8 && xi >= 1 && xi <= 32){
    size_t base = (((size_t)b*512 + 2*cp)*8 + (yy-1))*32 + (xi-1);
    v0 = feat[base];
    v1 = feat[base + 256];   // c+1 stride = 8*32
  }
  fT[idx] = packbf(v0, v1);
}

// ---------------- conv-weight transpose: Wf[a][c][t] -> wb[t][a][c] bf16 ----------------
__global__ __launch_bounds__(256) void k_tconv2(const float* __restrict__ Wf, uintT* __restrict__ wb){
  int idx = blockIdx.x*256 + threadIdx.x;  // 1,179,648 (grid 4608)
  int cp = idx & 255;
  int r  = idx >> 8;        // t*512 + a
  int a  = r & 511;
  int t  = r >> 9;
  float v0 = Wf[((size_t)a*512 + 2*cp)*9 + t];
  float v1 = Wf[((size_t)a*512 + 2*cp + 1)*9 + t];
  wb[idx] = packbf(v0, v1);
}

// ---------------- bf16 packers ----------------
__global__ __launch_bounds__(256) void k_wgate(const float* __restrict__ w0,
    const float* __restrict__ w1, const float* __restrict__ w2, uintT* __restrict__ o){
  int idx = blockIdx.x*256 + threadIdx.x;    // 1,572,864
  int m = idx >> 19, r = idx & 524287;
  const float* s = (m==0)? w0 : (m==1)? w1 : w2;
  float2 v = *(const float2*)(s + 2*(size_t)r);
  o[idx] = packbf(v.x, v.y);
}
__global__ __launch_bounds__(256) void k_woutb(const float* __restrict__ W, uintT* __restrict__ o){
  int idx = blockIdx.x*256 + threadIdx.x;    // 56,832
  float2 v = *(const float2*)(W + 2*(size_t)idx);
  o[idx] = packbf(v.x, v.y);
}
__global__ __launch_bounds__(256) void k_featb(const float* __restrict__ F, uintT* __restrict__ o){
  int idx = blockIdx.x*256 + threadIdx.x;    // 2,097,152
  float2 v = *(const float2*)(F + 2*(size_t)idx);
  o[idx] = packbf(v.x, v.y);
}
// WstT[u][ap] = pack(Wst[2ap][u], Wst[2ap+1][u])  (coalesced sp-GEMV layout)
__global__ __launch_bounds__(256) void k_wstT(const float* __restrict__ Wst, uintT* __restrict__ o){
  int idx = blockIdx.x*256 + threadIdx.x;    // 131,072
  int u = idx >> 8, ap = idx & 255;
  o[idx] = packbf(Wst[(size_t)(2*ap)*512 + u], Wst[(size_t)(2*ap+1)*512 + u]);
}

// ---------------- M0[j][g] = sum_k wih0[j][k]*Wemb[k][g] + bih0[j]+bhh0[j]; col 111 = bias-only ----------------
__global__ __launch_bounds__(128) void k_m0(const float* __restrict__ wih0,
                                            const float* __restrict__ Wemb,
                                            const float* __restrict__ bih0,
                                            const float* __restrict__ bhh0,
                                            float* __restrict__ M0){
  int j = blockIdx.x, g = threadIdx.x;
  float bs = bih0[j] + bhh0[j];
  if (g < V1){
    float acc = 0.f;
    const float* wr = wih0 + (size_t)j*512;
    for (int k=0;k<512;k++) acc += wr[k] * Wemb[(size_t)k*V1 + g];
    M0[(size_t)j*112 + g] = acc + bs;
  } else if (g == V1){
    M0[(size_t)j*112 + V1] = bs;
  }
}

// ---------------- MFMA conv (unchanged): 256 wgs, wg=(M 64 pos)x(N 256 a) ----------------
__global__ __launch_bounds__(256) void k_convm(const ushortT* __restrict__ fT,
                                               const ushortT* __restrict__ wb,
                                               const float* __restrict__ bfv,
                                               ushortT* __restrict__ fpj)
{
  __shared__ __align__(16) ushortT a_lds[136*72];   // 4 rows x 34 xi x 64c  (19,584 B)
  __shared__ __align__(16) ushortT b_lds[256*72];   // 256 a x 64 c          (36,864 B)
  const int tid = threadIdx.x;
  const int w   = tid >> 6;
  const int l   = tid & 63;
  const int kg  = l >> 4;
  const int ln  = l & 15;
  const int bid = blockIdx.x;
  const int nh  = bid & 1;
  const int mt  = bid >> 1;
  const int b   = mt >> 2;
  const int y0  = (mt & 3) * 2;
  const int a0  = nh * 256;

  f32x4 acc[4][4];
  #pragma unroll
  for (int nb=0; nb<4; nb++){
    float bv = bfv[a0 + w*64 + nb*16 + ln];
    #pragma unroll
    for (int mb=0; mb<4; mb++){
      acc[mb][nb][0]=bv; acc[mb][nb][1]=bv; acc[mb][nb][2]=bv; acc[mb][nb][3]=bv;
    }
  }

  const char* aSrc = (const char*)(fT + (((size_t)b*10 + y0)*34)*512);
  const char* wSrc = (const char*)wb;

  for (int c0 = 0; c0 < 512; c0 += 64){
    {
      const char* s = aSrc + (size_t)c0*2;
      #pragma unroll
      for (int i=0;i<4;i++){
        int idx = tid + i*256;
        int pos = idx >> 3, q = idx & 7;
        uint4 v = *(const uint4*)(s + (size_t)pos*1024 + q*16);
        *(uint4*)((char*)a_lds + pos*144 + q*16) = v;
      }
      if (tid < 64){
        int idx = 1024 + tid;
        int pos = idx >> 3, q = idx & 7;
        uint4 v = *(const uint4*)(s + (size_t)pos*1024 + q*16);
        *(uint4*)((char*)a_lds + pos*144 + q*16) = v;
      }
    }
    #pragma unroll
    for (int t=0; t<9; t++){
      const int ky = t/3, kx = t - (t/3)*3;
      {
        const char* s = wSrc + (((size_t)t*512 + a0)*512 + c0)*2;
        #pragma unroll
        for (int i=0;i<8;i++){
          int idx = tid + i*256;
          int ai = idx >> 3, q = idx & 7;
          uint4 v = *(const uint4*)(s + (size_t)ai*1024 + q*16);
          *(uint4*)((char*)b_lds + ai*144 + q*16) = v;
        }
      }
      __syncthreads();
      #pragma unroll
      for (int ks=0; ks<2; ks++){
        bf16x8 afr[4], bfr[4];
        #pragma unroll
        for (int mb=0; mb<4; mb++){
          int row = ((mb>>1) + ky)*34 + (mb&1)*16 + ln + kx;
          afr[mb] = *(const bf16x8*)((const char*)a_lds + row*144 + kg*16 + ks*64);
        }
        #pragma unroll
        for (int nb=0; nb<4; nb++){
          int ai = w*64 + nb*16 + ln;
          bfr[nb] = *(const bf16x8*)((const char*)b_lds + ai*144 + kg*16 + ks*64);
        }
        #pragma unroll
        for (int mb=0; mb<4; mb++)
          #pragma unroll
          for (int nb=0; nb<4; nb++)
            acc[mb][nb] = __builtin_amdgcn_mfma_f32_16x16x32_bf16(afr[mb], bfr[nb], acc[mb][nb], 0, 0, 0);
      }
      __syncthreads();
    }
  }

  #pragma unroll
  for (int mb=0; mb<4; mb++){
    #pragma unroll
    for (int nb=0; nb<4; nb++){
      int a = a0 + w*64 + nb*16 + ln;
      #pragma unroll
      for (int r4=0; r4<4; r4++){
        int pos = mb*16 + kg*4 + r4;
        fpj[((size_t)b*HWP + (y0*32 + pos))*512 + a] = f2b(acc[mb][nb][r4]);
      }
    }
  }
}

// ---------------- stage bf16 state [32 b][256 uints] coherent -> LDS [32][268] ----------------
__device__ __forceinline__ void stage_state_a(uintT* __restrict__ hs,
                                              uintT* __restrict__ src, int tid){
  #pragma unroll
  for (int i=0;i<16;i++){
    int g = tid + i*512;
    hs[(g >> 8)*268 + (g & 255)] = aload_u(&src[g]);
  }
}

// ---------------- fused step loop: 64 A + 64 B + 32 att blocks, 33 iterations ----------------
__global__ __launch_bounds__(512) void k_steps(
    const int* __restrict__ gt, const float* __restrict__ M0,
    const uintT* __restrict__ wgb,
    const float* __restrict__ bih1, const float* __restrict__ bhh1,
    const ushortT* __restrict__ featb, const ushortT* __restrict__ fpj,
    const uintT* __restrict__ WstTb, const float* __restrict__ watt,
    const uintT* __restrict__ Woutb, const float* __restrict__ bout,
    float* __restrict__ st, float* __restrict__ out)
{
  __shared__ __align__(16) float pool[POOLF];
  const int tid = threadIdx.x, bid = blockIdx.x;
  uintT* h0bf = (uintT*)st;            // 2 parities x [32 b][256 u] bf16
  uintT* h1bf = (uintT*)st + 16384;    // 2 parities x [32 b][256 u] bf16
  float* h1f  = st + 32768;            // 2 parities x [512 k][32 b] f32 (role C)
  float* c0T  = st + 65536;            // [512][32] block-private
  float* c1T  = st + 81920;            // [512][32] block-private

  const bool isGate = bid < 128;
  const bool isA    = bid < 64;

  // ---- gate-role constants + weights hoisted to VGPRs (L2/L3 read once) ----
  const int w   = tid >> 6;
  const int l   = tid & 63;
  const int kg  = l >> 4;
  const int ln  = l & 15;
  const int ks2 = w >> 2;
  const int rt  = (w >> 1) & 1;
  const int nh  = w & 1;
  const int u0g = (isA ? bid : bid - 64) * 8;
  const int jrow = (ln >> 2)*512 + u0g + rt*4 + (ln & 3);
  uint4 wA[8], wB1[8], wB2[8];
  if (isGate){
    if (isA){
      const uintT* wp = wgb + (size_t)jrow*256 + kg*4;
      #pragma unroll
      for (int s8=0; s8<8; s8++) wA[s8] = *(const uint4*)(wp + (ks2*8 + s8)*16);
    } else {
      const uintT* wp1 = wgb + 524288  + (size_t)jrow*256 + kg*4;
      const uintT* wp2 = wgb + 1048576 + (size_t)jrow*256 + kg*4;
      #pragma unroll
      for (int s8=0; s8<8; s8++){
        wB1[s8] = *(const uint4*)(wp1 + (ks2*8 + s8)*16);
        wB2[s8] = *(const uint4*)(wp2 + (ks2*8 + s8)*16);
      }
    }
  }

  cg::grid_group grid = cg::this_grid();

  for (int L = 0; L < STEPS + 2; L++){
    if (isGate){
      const int t = isA ? L : L - 1;
      if (t >= 0 && t <= STEPS-1){
        uintT* hs = (uintT*)pool;          // [32][268] staged state
        float* gs = pool + 8576;           // [2][32][33] partial D
        float* hv = pool + 10688;          // [8][33] new h staging
        const int u0 = u0g;
        const ushortT* hb = (const ushortT*)hs + (nh*16 + ln)*536 + kg*8;
        f32x4 acc = {0.f, 0.f, 0.f, 0.f};

        if (isA){
          stage_state_a(hs, h0bf + ((t+1)&1)*8192, tid);
          __syncthreads();
          #pragma unroll
          for (int s8=0; s8<8; s8++){
            int s = ks2*8 + s8;
            bf16x8 bfr = *(const bf16x8*)(hb + s*32);
            acc = __builtin_amdgcn_mfma_f32_16x16x32_bf16(u4_to_b8(wA[s8]), bfr, acc, 0, 0, 0);
          }
        } else {
          stage_state_a(hs, h0bf + (t&1)*8192, tid);
          __syncthreads();
          #pragma unroll
          for (int s8=0; s8<8; s8++){
            int s = ks2*8 + s8;
            bf16x8 bfr = *(const bf16x8*)(hb + s*32);
            acc = __builtin_amdgcn_mfma_f32_16x16x32_bf16(u4_to_b8(wB1[s8]), bfr, acc, 0, 0, 0);
          }
          __syncthreads();
          stage_state_a(hs, h1bf + ((t+1)&1)*8192, tid);
          __syncthreads();
          #pragma unroll
          for (int s8=0; s8<8; s8++){
            int s = ks2*8 + s8;
            bf16x8 bfr = *(const bf16x8*)(hb + s*32);
            acc = __builtin_amdgcn_mfma_f32_16x16x32_bf16(u4_to_b8(wB2[s8]), bfr, acc, 0, 0, 0);
          }
        }
        #pragma unroll
        for (int r=0;r<4;r++)
          gs[(ks2*32 + kg*8 + rt*4 + r)*33 + nh*16 + ln] = acc[r];
        __syncthreads();

        if (tid < 256){
          const int ul = tid >> 5, b = tid & 31, u = u0 + ul;
          float g4[4];
          #pragma unroll
          for (int g=0; g<4; g++){
            float sacc = gs[(g*8+ul)*33 + b] + gs[(32 + g*8+ul)*33 + b];
            int j = g*512 + u;
            if (isA){
              int sym = (t > 0) ? gt[b*STEPS + t - 1] : V1;
              sacc += M0[(size_t)j*112 + sym];
            } else {
              sacc += bih1[j] + bhh1[j];
            }
            g4[g] = sacc;
          }
          float* cT = isA ? c0T : c1T;
          int idx = u*32 + b;
          float cn = sigf(g4[1])*cT[idx] + sigf(g4[0])*tanh_f(g4[2]);
          cT[idx] = cn;                               // block-private, plain
          float h = sigf(g4[3])*tanh_f(cn);
          if (!isA) astore_f(&h1f[(t&1)*16384 + idx], h);
          hv[ul*33 + b] = h;
        }
        __syncthreads();
        if (tid < 128){
          const int up = tid >> 5, b = tid & 31;
          uintT* hw = (isA ? h0bf : h1bf) + (t&1)*8192;
          astore_u(&hw[b*256 + (u0>>1) + up],
                   packbf(hv[(up*2)*33 + b], hv[(up*2+1)*33 + b]));
        }
      }
    } else {
      // ======= role C: attention(r), r=L-2 =======
      const int r = L - 2;
      if (r >= 0 && r <= STEPS-1){
        const int b = bid - 128;
        float* h1s   = pool;
        float* spsl  = pool + 512;
        float* spA   = pool + 1024;
        float* spB   = pool + 1536;
        float* watts = pool + 2048;
        float* pals  = pool + 2560;
        float* attw  = pool + 3072;
        float* glim  = pool + 3328;
        float* red   = pool + 3840;

        float* h1c = h1f + (r&1)*16384;
        h1s[tid]   = aload_f(&h1c[tid*32 + b]);
        watts[tid] = watt[tid];
        __syncthreads();

        // sp[a] = sum_u WstT[u][a] * h1[u]
        {
          int ap = tid & 255, uh = tid >> 8;
          float s0 = 0.f, s1 = 0.f;
          const uintT* wp = WstTb + ((size_t)uh*256)*256 + ap;
          #pragma unroll 8
          for (int u=0; u<256; u++){
            uintT wv = wp[(size_t)u*256];
            float h = h1s[uh*256 + u];
            s0 += blo(wv)*h; s1 += bhi(wv)*h;
          }
          spA[tid] = s0; spB[tid] = s1;
        }
        __syncthreads();
        {
          int apx = tid >> 1, i = tid & 1;
          spsl[tid] = i ? (spB[apx] + spB[256+apx]) : (spA[apx] + spA[256+apx]);
        }
        __syncthreads();

        // attention logits over (p, a-half)
        {
          int p = tid & 255, ac = tid >> 8;
          const uint4* fr = (const uint4*)(fpj + ((size_t)b*HWP + p)*512 + ac*256);
          float al2 = 0.f;
          #pragma unroll 8
          for (int kb=0;kb<32;kb++){
            uint4 q = fr[kb];
            float v[8] = {blo(q.x),bhi(q.x),blo(q.y),bhi(q.y),blo(q.z),bhi(q.z),blo(q.w),bhi(q.w)};
            int a0 = ac*256 + kb*8;
            #pragma unroll
            for (int i=0;i<8;i++)
              al2 += watts[a0+i] * tanh_f(v[i] + spsl[a0+i]);
          }
          pals[tid] = al2;
        }
        __syncthreads();
        // softmax over 256 positions
        {
          float al2 = (tid < 256) ? (pals[tid] + pals[256+tid]) : -1e30f;
          float m = al2;
          #pragma unroll
          for (int off=32; off>0; off>>=1) m = fmaxf(m, __shfl_xor(m, off));
          if (tid < 256 && (tid & 63)==0) red[tid>>6] = m;
          __syncthreads();
          m = fmaxf(fmaxf(red[0],red[1]), fmaxf(red[2],red[3]));
          float e = (tid < 256) ? __expf(al2 - m) : 0.f;
          float s = e;
          #pragma unroll
          for (int off=32; off>0; off>>=1) s += __shfl_xor(s, off);
          __syncthreads();
          if (tid < 256 && (tid & 63)==0) red[tid>>6] = s;
          __syncthreads();
          if (tid < 256){
            float sa = red[0]+red[1]+red[2]+red[3];
            attw[tid] = e / sa;
          }
        }
        __syncthreads();
        // glimpse[c] = sum_p featb[b,c,p] * attw[p]
        {
          const uint4* fr = (const uint4*)(featb + ((size_t)b*512 + tid)*HWP);
          float acc = 0.f;
          #pragma unroll 8
          for (int kb=0;kb<32;kb++){
            uint4 q = fr[kb];
            const float* aw = attw + kb*8;
            acc += blo(q.x)*aw[0] + bhi(q.x)*aw[1] + blo(q.y)*aw[2] + bhi(q.y)*aw[3]
                 + blo(q.z)*aw[4] + bhi(q.z)*aw[5] + blo(q.w)*aw[6] + bhi(q.w)*aw[7];
          }
          glim[tid] = acc;
        }
        __syncthreads();
        // logits = [h1, glimpse] @ Wout^T + b_out
        if (tid < V1){
          const uint4* wr = (const uint4*)(Woutb + (size_t)tid*512);
          float acc = bout[tid];
          #pragma unroll 8
          for (int kb=0;kb<64;kb++){
            uint4 q = wr[kb];
            const float* hx = h1s + kb*8;
            acc += blo(q.x)*hx[0] + bhi(q.x)*hx[1] + blo(q.y)*hx[2] + bhi(q.y)*hx[3]
                 + blo(q.z)*hx[4] + bhi(q.z)*hx[5] + blo(q.w)*hx[6] + bhi(q.w)*hx[7];
          }
          #pragma unroll 8
          for (int kb=0;kb<64;kb++){
            uint4 q = wr[64+kb];
            const float* gx = glim + kb*8;
            acc += blo(q.x)*gx[0] + bhi(q.x)*gx[1] + blo(q.y)*gx[2] + bhi(q.y)*gx[3]
                 + blo(q.z)*gx[4] + bhi(q.z)*gx[5] + blo(q.w)*gx[6] + bhi(q.w)*gx[7];
          }
          out[(size_t)b*STEPS*V1 + (size_t)r*V1 + tid] = acc;
        }
        __syncthreads();   // protect pool before next iteration's reuse
      }
    }
    if (L < STEPS + 1) grid.sync();
  }
}

extern "C" void kernel_launch(void* const* d_in, const int* in_sizes, int n_in,
                              void* d_out, int out_size, void* d_ws, size_t ws_size,
                              hipStream_t stream)
{
  const float* features = (const float*)d_in[0];
  const int*   gt       = (const int*)d_in[2];
  const float* Wf    = (const float*)d_in[3];
  const float* bfv   = (const float*)d_in[4];
  const float* Wst   = (const float*)d_in[5];
  const float* watt  = (const float*)d_in[6];
  const float* Wemb  = (const float*)d_in[7];
  const float* wih0  = (const float*)d_in[8];
  const float* whh0  = (const float*)d_in[9];
  const float* bih0  = (const float*)d_in[10];
  const float* bhh0  = (const float*)d_in[11];
  const float* wih1  = (const float*)d_in[12];
  const float* whh1  = (const float*)d_in[13];
  const float* bih1  = (const float*)d_in[14];
  const float* bhh1  = (const float*)d_in[15];
  const float* Wout  = (const float*)d_in[16];
  const float* bout  = (const float*)d_in[17];
  float* out = (float*)d_out;

  // ---- workspace layout (bytes), total 25,133,056 (unchanged footprint) ----
  char* wsb = (char*)d_ws;
  ushortT* fpj   = (ushortT*)(wsb + 0);          //  8,388,608 persist
  ushortT* featb = (ushortT*)(wsb + 8388608);    //  8,388,608 persist (written after conv)
  float*   M0    = (float*)  (wsb + 16777216);   //    917,504 (incl. bias col 111)
  uintT*   wgb   = (uintT*)  (wsb + 17694720);   //  6,291,456 (whh0|wih1|whh1 bf16)
  uintT*   Woutb = (uintT*)  (wsb + 23986176);   //    227,328 (pad to 229,376)
  uintT*   WstTb = (uintT*)  (wsb + 24215552);   //    524,288
  float*   st    = (float*)  (wsb + 24739840);   //    393,216 (h0bf x2, h1bf x2, h1f x2, c0, c1)
  // transients (dead after k_convm; overlay featb/M0/wgb/Woutb/WstTb region):
  uintT*   fTt   = (uintT*)  (wsb + 8388608);    // 11,141,120 bf16 featTp
  ushortT* wbt   = (ushortT*)(wsb + 19529728);   //  4,718,592 bf16 wb[t][a][c] (ends 24,248,320)

  k_init  <<<384,   256, 0, stream>>>(st);
  k_featT <<<10880, 256, 0, stream>>>(features, fTt);
  k_tconv2<<<4608,  256, 0, stream>>>(Wf, (uintT*)wbt);
  k_convm <<<256,   256, 0, stream>>>((const ushortT*)fTt, wbt, bfv, fpj);
  // packers run AFTER conv (their regions overlay the conv transients)
  k_wgate <<<6144,  256, 0, stream>>>(whh0, wih1, whh1, wgb);
  k_wstT  <<<512,   256, 0, stream>>>(Wst, WstTb);
  k_woutb <<<222,   256, 0, stream>>>(Wout, Woutb);
  k_m0    <<<2048,  128, 0, stream>>>(wih0, Wemb, bih0, bhh0, M0);
  k_featb <<<8192,  256, 0, stream>>>(features, (uintT*)featb);

  {
    void* args[] = {
      (void*)&gt, (void*)&M0, (void*)&wgb, (void*)&bih1, (void*)&bhh1,
      (void*)&featb, (void*)&fpj, (void*)&WstTb, (void*)&watt,
      (void*)&Woutb, (void*)&bout, (void*)&st, (void*)&out
    };
    hipLaunchCooperativeKernel((const void*)k_steps, dim3(NWG), dim3(512),
                               args, 0, stream);
  }
  (void)in_sizes; (void)n_in; (void)out_size; (void)ws_size;
}

// Round 5
// 1593.660 us; speedup vs baseline: 1.4527x; 1.4527x over previous
//
#include <hip/hip_runtime.h>
#include <hip/hip_bf16.h>

// SARDecoder round 13: back to verified multi-launch (r10 structure); role C
// critical-path cut. (r12 coop fused was correct but grid.sync's per-iter L2
// writeback+invalidate cost more than kernel boundaries.) Changes vs r10:
// (1) role C reads h1 as bf16 [b][256 uints] (1KB coalesced) -- h1f f32 copy
// deleted; (2) sp GEMV: uint4 weight loads, 8 u-range partials over all 512
// threads + LDS reduce; (3) out-proj 4x parallel over k-quarters + LDS reduce.
// Roles A/B, conv, prep byte-identical to the round-2-verified kernel.

#define RNN   512
#define V1    111
#define STEPS 31
#define HWP   256
#define POOLF 11008

typedef unsigned short ushortT;
typedef unsigned int   uintT;
typedef __attribute__((ext_vector_type(8))) short bf16x8;   // 8 bf16 (4 VGPRs)
typedef __attribute__((ext_vector_type(4))) float f32x4;

__device__ __forceinline__ float blo(uintT u){ union { uintT i; float f; } v; v.i = u << 16; return v.f; }
__device__ __forceinline__ float bhi(uintT u){ union { uintT i; float f; } v; v.i = u & 0xffff0000u; return v.f; }
__device__ __forceinline__ ushortT f2b(float f){
  __hip_bfloat16 h = __float2bfloat16(f);
  union { __hip_bfloat16 b; ushortT s; } v; v.b = h; return v.s;
}
__device__ __forceinline__ uintT packbf(float lo, float hi){
  return (uintT)f2b(lo) | ((uintT)f2b(hi) << 16);
}
__device__ __forceinline__ bf16x8 u4_to_b8(uint4 u){
  union { uint4 a; bf16x8 b; } v; v.a = u; return v.b;
}
__device__ __forceinline__ float sigf(float x){ return 1.f/(1.f + __expf(-x)); }
__device__ __forceinline__ float tanh_f(float x){ float e = __expf(2.f*x); return 1.f - 2.f/(e+1.f); }

// ---------------- init: zero states (65536 f32 = 256 KB: h0bf x2, h1bf x2, c0, c1) ----------------
__global__ __launch_bounds__(256) void k_init(float* __restrict__ p){
  p[blockIdx.x*256 + threadIdx.x] = 0.f;   // grid 256
}

// ---------------- featT: features fp32 [b][c][y][x] -> bf16 [b][yy0..9][xi0..33][c], zero halo ----------------
__global__ __launch_bounds__(256) void k_featT(const float* __restrict__ feat, uintT* __restrict__ fT){
  int idx = blockIdx.x*256 + threadIdx.x;   // 2,785,280 (grid 10880)
  int cp = idx & 255;
  int r  = idx >> 8;         // b*340 + yy*34 + xi
  int xi = r % 34;
  int q  = r / 34;
  int yy = q % 10;
  int b  = q / 10;
  float v0 = 0.f, v1 = 0.f;
  if (yy >= 1 && yy <= 8 && xi >= 1 && xi <= 32){
    size_t base = (((size_t)b*512 + 2*cp)*8 + (yy-1))*32 + (xi-1);
    v0 = feat[base];
    v1 = feat[base + 256];   // c+1 stride = 8*32
  }
  fT[idx] = packbf(v0, v1);
}

// ---------------- conv-weight transpose: Wf[a][c][t] -> wb[t][a][c] bf16 ----------------
__global__ __launch_bounds__(256) void k_tconv2(const float* __restrict__ Wf, uintT* __restrict__ wb){
  int idx = blockIdx.x*256 + threadIdx.x;  // 1,179,648 (grid 4608)
  int cp = idx & 255;
  int r  = idx >> 8;        // t*512 + a
  int a  = r & 511;
  int t  = r >> 9;
  float v0 = Wf[((size_t)a*512 + 2*cp)*9 + t];
  float v1 = Wf[((size_t)a*512 + 2*cp + 1)*9 + t];
  wb[idx] = packbf(v0, v1);
}

// ---------------- bf16 packers ----------------
__global__ __launch_bounds__(256) void k_wgate(const float* __restrict__ w0,
    const float* __restrict__ w1, const float* __restrict__ w2, uintT* __restrict__ o){
  int idx = blockIdx.x*256 + threadIdx.x;    // 1,572,864
  int m = idx >> 19, r = idx & 524287;
  const float* s = (m==0)? w0 : (m==1)? w1 : w2;
  float2 v = *(const float2*)(s + 2*(size_t)r);
  o[idx] = packbf(v.x, v.y);
}
__global__ __launch_bounds__(256) void k_woutb(const float* __restrict__ W, uintT* __restrict__ o){
  int idx = blockIdx.x*256 + threadIdx.x;    // 56,832
  float2 v = *(const float2*)(W + 2*(size_t)idx);
  o[idx] = packbf(v.x, v.y);
}
__global__ __launch_bounds__(256) void k_featb(const float* __restrict__ F, uintT* __restrict__ o){
  int idx = blockIdx.x*256 + threadIdx.x;    // 2,097,152
  float2 v = *(const float2*)(F + 2*(size_t)idx);
  o[idx] = packbf(v.x, v.y);
}
// WstT[u][ap] = pack(Wst[2ap][u], Wst[2ap+1][u])  (coalesced sp-GEMV layout)
__global__ __launch_bounds__(256) void k_wstT(const float* __restrict__ Wst, uintT* __restrict__ o){
  int idx = blockIdx.x*256 + threadIdx.x;    // 131,072
  int u = idx >> 8, ap = idx & 255;
  o[idx] = packbf(Wst[(size_t)(2*ap)*512 + u], Wst[(size_t)(2*ap+1)*512 + u]);
}

// ---------------- M0[j][g] = sum_k wih0[j][k]*Wemb[k][g] + bih0[j]+bhh0[j]; col 111 = bias-only ----------------
__global__ __launch_bounds__(128) void k_m0(const float* __restrict__ wih0,
                                            const float* __restrict__ Wemb,
                                            const float* __restrict__ bih0,
                                            const float* __restrict__ bhh0,
                                            float* __restrict__ M0){
  int j = blockIdx.x, g = threadIdx.x;
  float bs = bih0[j] + bhh0[j];
  if (g < V1){
    float acc = 0.f;
    const float* wr = wih0 + (size_t)j*512;
    for (int k=0;k<512;k++) acc += wr[k] * Wemb[(size_t)k*V1 + g];
    M0[(size_t)j*112 + g] = acc + bs;
  } else if (g == V1){
    M0[(size_t)j*112 + V1] = bs;
  }
}

// ---------------- MFMA conv (unchanged): 256 wgs, wg=(M 64 pos)x(N 256 a) ----------------
__global__ __launch_bounds__(256) void k_convm(const ushortT* __restrict__ fT,
                                               const ushortT* __restrict__ wb,
                                               const float* __restrict__ bfv,
                                               ushortT* __restrict__ fpj)
{
  __shared__ __align__(16) ushortT a_lds[136*72];   // 4 rows x 34 xi x 64c  (19,584 B)
  __shared__ __align__(16) ushortT b_lds[256*72];   // 256 a x 64 c          (36,864 B)
  const int tid = threadIdx.x;
  const int w   = tid >> 6;
  const int l   = tid & 63;
  const int kg  = l >> 4;
  const int ln  = l & 15;
  const int bid = blockIdx.x;
  const int nh  = bid & 1;
  const int mt  = bid >> 1;
  const int b   = mt >> 2;
  const int y0  = (mt & 3) * 2;
  const int a0  = nh * 256;

  f32x4 acc[4][4];
  #pragma unroll
  for (int nb=0; nb<4; nb++){
    float bv = bfv[a0 + w*64 + nb*16 + ln];
    #pragma unroll
    for (int mb=0; mb<4; mb++){
      acc[mb][nb][0]=bv; acc[mb][nb][1]=bv; acc[mb][nb][2]=bv; acc[mb][nb][3]=bv;
    }
  }

  const char* aSrc = (const char*)(fT + (((size_t)b*10 + y0)*34)*512);
  const char* wSrc = (const char*)wb;

  for (int c0 = 0; c0 < 512; c0 += 64){
    {
      const char* s = aSrc + (size_t)c0*2;
      #pragma unroll
      for (int i=0;i<4;i++){
        int idx = tid + i*256;
        int pos = idx >> 3, q = idx & 7;
        uint4 v = *(const uint4*)(s + (size_t)pos*1024 + q*16);
        *(uint4*)((char*)a_lds + pos*144 + q*16) = v;
      }
      if (tid < 64){
        int idx = 1024 + tid;
        int pos = idx >> 3, q = idx & 7;
        uint4 v = *(const uint4*)(s + (size_t)pos*1024 + q*16);
        *(uint4*)((char*)a_lds + pos*144 + q*16) = v;
      }
    }
    #pragma unroll
    for (int t=0; t<9; t++){
      const int ky = t/3, kx = t - (t/3)*3;
      {
        const char* s = wSrc + (((size_t)t*512 + a0)*512 + c0)*2;
        #pragma unroll
        for (int i=0;i<8;i++){
          int idx = tid + i*256;
          int ai = idx >> 3, q = idx & 7;
          uint4 v = *(const uint4*)(s + (size_t)ai*1024 + q*16);
          *(uint4*)((char*)b_lds + ai*144 + q*16) = v;
        }
      }
      __syncthreads();
      #pragma unroll
      for (int ks=0; ks<2; ks++){
        bf16x8 afr[4], bfr[4];
        #pragma unroll
        for (int mb=0; mb<4; mb++){
          int row = ((mb>>1) + ky)*34 + (mb&1)*16 + ln + kx;
          afr[mb] = *(const bf16x8*)((const char*)a_lds + row*144 + kg*16 + ks*64);
        }
        #pragma unroll
        for (int nb=0; nb<4; nb++){
          int ai = w*64 + nb*16 + ln;
          bfr[nb] = *(const bf16x8*)((const char*)b_lds + ai*144 + kg*16 + ks*64);
        }
        #pragma unroll
        for (int mb=0; mb<4; mb++)
          #pragma unroll
          for (int nb=0; nb<4; nb++)
            acc[mb][nb] = __builtin_amdgcn_mfma_f32_16x16x32_bf16(afr[mb], bfr[nb], acc[mb][nb], 0, 0, 0);
      }
      __syncthreads();
    }
  }

  #pragma unroll
  for (int mb=0; mb<4; mb++){
    #pragma unroll
    for (int nb=0; nb<4; nb++){
      int a = a0 + w*64 + nb*16 + ln;
      #pragma unroll
      for (int r4=0; r4<4; r4++){
        int pos = mb*16 + kg*4 + r4;
        fpj[((size_t)b*HWP + (y0*32 + pos))*512 + a] = f2b(acc[mb][nb][r4]);
      }
    }
  }
}

// ---------------- stage bf16 state [32 b][256 uints] global -> LDS [32][268] (padded) ----------------
__device__ __forceinline__ void stage_state(uintT* __restrict__ hs,
                                            const uintT* __restrict__ src, int tid){
  #pragma unroll
  for (int i=0;i<16;i++){
    int g = tid + i*512;
    hs[(g >> 8)*268 + (g & 255)] = src[g];
  }
}

// ---------------- one pipeline stage: 64 A + 64 B + 32 att blocks (512 thr) ----------------
__global__ __launch_bounds__(512) void k_step(int L,
    const int* __restrict__ gt, const float* __restrict__ M0,
    const uintT* __restrict__ wgb,
    const float* __restrict__ bih1, const float* __restrict__ bhh1,
    const ushortT* __restrict__ featb, const ushortT* __restrict__ fpj,
    const uintT* __restrict__ WstTb, const float* __restrict__ watt,
    const uintT* __restrict__ Woutb, const float* __restrict__ bout,
    float* __restrict__ st, float* __restrict__ out)
{
  __shared__ __align__(16) float pool[POOLF];
  const int tid = threadIdx.x, bid = blockIdx.x;
  // state layout (st = 65536 floats = 256 KB):
  uintT* h0bf = (uintT*)st;            // 2 parities x [32 b][256 u] bf16
  uintT* h1bf = (uintT*)st + 16384;    // 2 parities x [32 b][256 u] bf16
  float* c0T  = st + 32768;            // [512][32] block-private
  float* c1T  = st + 49152;            // [512][32] block-private

  if (bid < 128){
    // ======= roles A/B: MFMA gate GEMMs (verbatim r10) =======
    uintT* hs = (uintT*)pool;          // [32][268] staged state
    float* gs = pool + 8576;           // [2][32][33] partial D
    float* hv = pool + 10688;          // [8][33] new h staging

    const int w   = tid >> 6;          // wave 0..7
    const int l   = tid & 63;
    const int kg  = l >> 4;
    const int ln  = l & 15;
    const int ks2 = w >> 2;
    const int rt  = (w >> 1) & 1;
    const int nh  = w & 1;
    const bool isA = bid < 64;
    const int u0 = (isA ? bid : bid - 64) * 8;
    const int t  = isA ? L : L - 1;
    if (t < 0 || t > STEPS-1) return;

    const int jrow = (ln >> 2)*512 + u0 + rt*4 + (ln & 3);
    const ushortT* hb = (const ushortT*)hs + (nh*16 + ln)*536 + kg*8;

    f32x4 acc = {0.f, 0.f, 0.f, 0.f};

    if (isA){
      stage_state(hs, h0bf + ((t+1)&1)*8192, tid);
      __syncthreads();
      const uintT* wp = wgb + (size_t)jrow*256 + kg*4;          // whh0
      #pragma unroll
      for (int s8=0; s8<8; s8++){
        int s = ks2*8 + s8;
        uint4 aw = *(const uint4*)(wp + s*16);
        bf16x8 bfr = *(const bf16x8*)(hb + s*32);
        acc = __builtin_amdgcn_mfma_f32_16x16x32_bf16(u4_to_b8(aw), bfr, acc, 0, 0, 0);
      }
    } else {
      stage_state(hs, h0bf + (t&1)*8192, tid);
      __syncthreads();
      const uintT* wp1 = wgb + 524288 + (size_t)jrow*256 + kg*4;  // wih1
      #pragma unroll
      for (int s8=0; s8<8; s8++){
        int s = ks2*8 + s8;
        uint4 aw = *(const uint4*)(wp1 + s*16);
        bf16x8 bfr = *(const bf16x8*)(hb + s*32);
        acc = __builtin_amdgcn_mfma_f32_16x16x32_bf16(u4_to_b8(aw), bfr, acc, 0, 0, 0);
      }
      __syncthreads();
      stage_state(hs, h1bf + ((t+1)&1)*8192, tid);
      __syncthreads();
      const uintT* wp2 = wgb + 1048576 + (size_t)jrow*256 + kg*4; // whh1
      #pragma unroll
      for (int s8=0; s8<8; s8++){
        int s = ks2*8 + s8;
        uint4 aw = *(const uint4*)(wp2 + s*16);
        bf16x8 bfr = *(const bf16x8*)(hb + s*32);
        acc = __builtin_amdgcn_mfma_f32_16x16x32_bf16(u4_to_b8(aw), bfr, acc, 0, 0, 0);
      }
    }
    #pragma unroll
    for (int r=0;r<4;r++)
      gs[(ks2*32 + kg*8 + rt*4 + r)*33 + nh*16 + ln] = acc[r];
    __syncthreads();

    if (tid < 256){
      const int ul = tid >> 5, b = tid & 31, u = u0 + ul;
      float g4[4];
      #pragma unroll
      for (int g=0; g<4; g++){
        float sacc = gs[(g*8+ul)*33 + b] + gs[(32 + g*8+ul)*33 + b];
        int j = g*512 + u;
        if (isA){
          int sym = (t > 0) ? gt[b*STEPS + t - 1] : V1;
          sacc += M0[(size_t)j*112 + sym];
        } else {
          sacc += bih1[j] + bhh1[j];
        }
        g4[g] = sacc;
      }
      float* cT = isA ? c0T : c1T;
      int idx = u*32 + b;
      float cn = sigf(g4[1])*cT[idx] + sigf(g4[0])*tanh_f(g4[2]);
      cT[idx] = cn;
      float h = sigf(g4[3])*tanh_f(cn);
      hv[ul*33 + b] = h;
    }
    __syncthreads();
    if (tid < 128){
      const int up = tid >> 5, b = tid & 31;
      uintT* hw = (isA ? h0bf : h1bf) + (t&1)*8192;
      hw[b*256 + (u0>>1) + up] = packbf(hv[(up*2)*33 + b], hv[(up*2+1)*33 + b]);
    }
    return;
  }

  // ======= role C: attention(r), r=L-2; h1 read as bf16 =======
  const int r = L - 2;
  if (r < 0 || r > STEPS-1) return;
  const int b = bid - 128;
  float* h1s   = pool;            // 512
  float* spsl  = pool + 512;      // 512
  float* watts = pool + 1024;     // 512
  float* pals  = pool + 1536;     // 512
  float* attw  = pool + 2048;     // 256
  float* glim  = pool + 2304;     // 512
  float* red   = pool + 2816;     // 64
  float* opart = pool + 2880;     // 512
  float* sppt  = pool + 3392;     // 4096 (8 uq x 512 a)

  if (tid < 256){
    uintT hvw = h1bf[(r&1)*8192 + b*256 + tid];   // word w <-> units 2w, 2w+1
    h1s[2*tid]   = blo(hvw);
    h1s[2*tid+1] = bhi(hvw);
  }
  watts[tid] = watt[tid];
  __syncthreads();

  // sp partials: 8 u-ranges x 512 a; uint4 weight loads (64/thread)
  {
    int ap4 = tid & 63, uq = tid >> 6;
    float a8[8] = {0.f,0.f,0.f,0.f,0.f,0.f,0.f,0.f};
    const uint4* wp = (const uint4*)(WstTb + (size_t)(uq*64)*256) + ap4;
    const float* hq = h1s + uq*64;
    #pragma unroll 8
    for (int u=0; u<64; u++){
      uint4 q = wp[(size_t)u*64];
      float h = hq[u];
      a8[0] += blo(q.x)*h; a8[1] += bhi(q.x)*h;
      a8[2] += blo(q.y)*h; a8[3] += bhi(q.y)*h;
      a8[4] += blo(q.z)*h; a8[5] += bhi(q.z)*h;
      a8[6] += blo(q.w)*h; a8[7] += bhi(q.w)*h;
    }
    #pragma unroll
    for (int j=0;j<8;j++) sppt[uq*512 + ap4*8 + j] = a8[j];
  }
  __syncthreads();
  {
    float s = 0.f;
    #pragma unroll
    for (int uq=0;uq<8;uq++) s += sppt[uq*512 + tid];
    spsl[tid] = s;
  }
  __syncthreads();

  // attention logits over (p, a-half)
  {
    int p = tid & 255, ac = tid >> 8;
    const uint4* fr = (const uint4*)(fpj + ((size_t)b*HWP + p)*512 + ac*256);
    float al2 = 0.f;
    #pragma unroll 8
    for (int kb=0;kb<32;kb++){
      uint4 q = fr[kb];
      float v[8] = {blo(q.x),bhi(q.x),blo(q.y),bhi(q.y),blo(q.z),bhi(q.z),blo(q.w),bhi(q.w)};
      int a0 = ac*256 + kb*8;
      #pragma unroll
      for (int i=0;i<8;i++)
        al2 += watts[a0+i] * tanh_f(v[i] + spsl[a0+i]);
    }
    pals[tid] = al2;
  }
  __syncthreads();
  // softmax over 256 positions
  {
    float al2 = (tid < 256) ? (pals[tid] + pals[256+tid]) : -1e30f;
    float m = al2;
    #pragma unroll
    for (int off=32; off>0; off>>=1) m = fmaxf(m, __shfl_xor(m, off));
    if (tid < 256 && (tid & 63)==0) red[tid>>6] = m;
    __syncthreads();
    m = fmaxf(fmaxf(red[0],red[1]), fmaxf(red[2],red[3]));
    float e = (tid < 256) ? __expf(al2 - m) : 0.f;
    float s = e;
    #pragma unroll
    for (int off=32; off>0; off>>=1) s += __shfl_xor(s, off);
    __syncthreads();
    if (tid < 256 && (tid & 63)==0) red[tid>>6] = s;
    __syncthreads();
    if (tid < 256){
      float sa = red[0]+red[1]+red[2]+red[3];
      attw[tid] = e / sa;
    }
  }
  __syncthreads();
  // glimpse[c] = sum_p featb[b,c,p] * attw[p]
  {
    const uint4* fr = (const uint4*)(featb + ((size_t)b*512 + tid)*HWP);
    float acc = 0.f;
    #pragma unroll 8
    for (int kb=0;kb<32;kb++){
      uint4 q = fr[kb];
      const float* aw = attw + kb*8;
      acc += blo(q.x)*aw[0] + bhi(q.x)*aw[1] + blo(q.y)*aw[2] + bhi(q.y)*aw[3]
           + blo(q.z)*aw[4] + bhi(q.z)*aw[5] + blo(q.w)*aw[6] + bhi(q.w)*aw[7];
    }
    glim[tid] = acc;
  }
  __syncthreads();
  // logits = [h1, glimpse] @ Wout^T + b_out; 4x parallel over k-quarters
  {
    int q = tid >> 7, o = tid & 127;
    float acc = 0.f;
    if (o < V1){
      const uint4* wr4 = (const uint4*)(Woutb + (size_t)o*512 + q*128);
      const float* src = (q < 2) ? (h1s + q*256) : (glim + (q-2)*256);
      #pragma unroll 8
      for (int kb=0;kb<32;kb++){
        uint4 w4 = wr4[kb];
        const float* sx = src + kb*8;
        acc += blo(w4.x)*sx[0] + bhi(w4.x)*sx[1] + blo(w4.y)*sx[2] + bhi(w4.y)*sx[3]
             + blo(w4.z)*sx[4] + bhi(w4.z)*sx[5] + blo(w4.w)*sx[6] + bhi(w4.w)*sx[7];
      }
    }
    opart[tid] = acc;
  }
  __syncthreads();
  if (tid < V1){
    float acc = bout[tid] + opart[tid] + opart[128+tid] + opart[256+tid] + opart[384+tid];
    out[(size_t)b*STEPS*V1 + (size_t)r*V1 + tid] = acc;
  }
}

extern "C" void kernel_launch(void* const* d_in, const int* in_sizes, int n_in,
                              void* d_out, int out_size, void* d_ws, size_t ws_size,
                              hipStream_t stream)
{
  const float* features = (const float*)d_in[0];
  const int*   gt       = (const int*)d_in[2];
  const float* Wf    = (const float*)d_in[3];
  const float* bfv   = (const float*)d_in[4];
  const float* Wst   = (const float*)d_in[5];
  const float* watt  = (const float*)d_in[6];
  const float* Wemb  = (const float*)d_in[7];
  const float* wih0  = (const float*)d_in[8];
  const float* whh0  = (const float*)d_in[9];
  const float* bih0  = (const float*)d_in[10];
  const float* bhh0  = (const float*)d_in[11];
  const float* wih1  = (const float*)d_in[12];
  const float* whh1  = (const float*)d_in[13];
  const float* bih1  = (const float*)d_in[14];
  const float* bhh1  = (const float*)d_in[15];
  const float* Wout  = (const float*)d_in[16];
  const float* bout  = (const float*)d_in[17];
  float* out = (float*)d_out;

  // ---- workspace layout (bytes), total ~25.1 MB (unchanged footprint) ----
  char* wsb = (char*)d_ws;
  ushortT* fpj   = (ushortT*)(wsb + 0);          //  8,388,608 persist
  ushortT* featb = (ushortT*)(wsb + 8388608);    //  8,388,608 persist (written after conv)
  float*   M0    = (float*)  (wsb + 16777216);   //    917,504 (incl. bias col 111)
  uintT*   wgb   = (uintT*)  (wsb + 17694720);   //  6,291,456 (whh0|wih1|whh1 bf16)
  uintT*   Woutb = (uintT*)  (wsb + 23986176);   //    227,328 (pad to 229,376)
  uintT*   WstTb = (uintT*)  (wsb + 24215552);   //    524,288
  float*   st    = (float*)  (wsb + 24739840);   //    262,144 (h0bf x2, h1bf x2, c0, c1)
  // transients (dead after k_convm; overlay featb/M0/wgb/Woutb/WstTb region):
  uintT*   fTt   = (uintT*)  (wsb + 8388608);    // 11,141,120 bf16 featTp
  ushortT* wbt   = (ushortT*)(wsb + 19529728);   //  4,718,592 bf16 wb[t][a][c] (ends 24,248,320)

  k_init  <<<256,   256, 0, stream>>>(st);
  k_featT <<<10880, 256, 0, stream>>>(features, fTt);
  k_tconv2<<<4608,  256, 0, stream>>>(Wf, (uintT*)wbt);
  k_convm <<<256,   256, 0, stream>>>((const ushortT*)fTt, wbt, bfv, fpj);
  // packers run AFTER conv (their regions overlay the conv transients)
  k_wgate <<<6144,  256, 0, stream>>>(whh0, wih1, whh1, wgb);
  k_wstT  <<<512,   256, 0, stream>>>(Wst, WstTb);
  k_woutb <<<222,   256, 0, stream>>>(Wout, Woutb);
  k_m0    <<<2048,  128, 0, stream>>>(wih0, Wemb, bih0, bhh0, M0);
  k_featb <<<8192,  256, 0, stream>>>(features, (uintT*)featb);

  for (int L = 0; L < STEPS + 2; L++){
    k_step<<<160, 512, 0, stream>>>(L, gt, M0, wgb, bih1, bhh1,
                                    featb, fpj, WstTb, watt, Woutb, bout, st, out);
  }
  (void)in_sizes; (void)n_in; (void)out_size; (void)ws_size;
}

// Round 6
// 799.627 us; speedup vs baseline: 2.8953x; 1.9930x over previous
//
#include <hip/hip_runtime.h>
#include <hip/hip_bf16.h>

// SARDecoder round 14: (1) attention DECOUPLED from recurrence (teacher
// forcing: scan carry never reads logits) -> phase 1 = roles A/B only logging
// h1 history; phase 2 = ONE parallel launch (992 blocks) of the verified
// role-C body, glimpse reads f32 features directly (featb deleted).
// (2) fence-free persistent phase 1 with SYSTEM-scope relaxed atomics:
// r11's race isolated to agent-scope L2 non-coherence (dirty-local-L2 writes
// invisible remotely; stale local copies unsnooped); sc1 system ops bypass L2
// both ways. Cumulative 8-counter barrier (logic race-free by induction),
// release = __syncthreads vmcnt-drain before bump. Cooperative launch for
// co-residency guarantee only (no grid.sync). No L2 invalidates -> weights/
// M0/gt stay L2-hot across all 31 iterations.

#define RNN   512
#define V1    111
#define STEPS 31
#define HWP   256
#define POOLF 11008
#define NWG   128

typedef unsigned short ushortT;
typedef unsigned int   uintT;
typedef __attribute__((ext_vector_type(8))) short bf16x8;   // 8 bf16 (4 VGPRs)
typedef __attribute__((ext_vector_type(4))) float f32x4;

__device__ __forceinline__ float blo(uintT u){ union { uintT i; float f; } v; v.i = u << 16; return v.f; }
__device__ __forceinline__ float bhi(uintT u){ union { uintT i; float f; } v; v.i = u & 0xffff0000u; return v.f; }
__device__ __forceinline__ ushortT f2b(float f){
  __hip_bfloat16 h = __float2bfloat16(f);
  union { __hip_bfloat16 b; ushortT s; } v; v.b = h; return v.s;
}
__device__ __forceinline__ uintT packbf(float lo, float hi){
  return (uintT)f2b(lo) | ((uintT)f2b(hi) << 16);
}
__device__ __forceinline__ bf16x8 u4_to_b8(uint4 u){
  union { uint4 a; bf16x8 b; } v; v.a = u; return v.b;
}
__device__ __forceinline__ float sigf(float x){ return 1.f/(1.f + __expf(-x)); }
__device__ __forceinline__ float tanh_f(float x){ float e = __expf(2.f*x); return 1.f - 2.f/(e+1.f); }

// ---- SYSTEM-scope relaxed atomics: bypass L2 both directions (MALL-coherent) ----
__device__ __forceinline__ uintT sload_u(const uintT* p){
  return __hip_atomic_load((uintT*)p, __ATOMIC_RELAXED, __HIP_MEMORY_SCOPE_SYSTEM);
}
__device__ __forceinline__ void sstore_u(uintT* p, uintT v){
  __hip_atomic_store(p, v, __ATOMIC_RELAXED, __HIP_MEMORY_SCOPE_SYSTEM);
}

// ---------------- init (run AFTER conv: regions overlay conv transients) ----------------
__global__ __launch_bounds__(256) void k_init(float* __restrict__ st,
                                              uintT* __restrict__ h1hist,
                                              uintT* __restrict__ bar){
  int bid = blockIdx.x;          // grid 225
  if (bid < 192)      st[bid*256 + threadIdx.x] = 0.f;                 // h0bf x2, c0, c1
  else if (bid < 224) h1hist[(bid-192)*256 + threadIdx.x] = 0u;        // slot 0 = h1(-1) = 0
  else if (threadIdx.x < 8) bar[threadIdx.x*32] = 0u;                  // 8 counters
}

// ---------------- featT: features fp32 [b][c][y][x] -> bf16 [b][yy0..9][xi0..33][c], zero halo ----------------
__global__ __launch_bounds__(256) void k_featT(const float* __restrict__ feat, uintT* __restrict__ fT){
  int idx = blockIdx.x*256 + threadIdx.x;   // 2,785,280 (grid 10880)
  int cp = idx & 255;
  int r  = idx >> 8;         // b*340 + yy*34 + xi
  int xi = r % 34;
  int q  = r / 34;
  int yy = q % 10;
  int b  = q / 10;
  float v0 = 0.f, v1 = 0.f;
  if (yy >= 1 && yy <= 8 && xi >= 1 && xi <= 32){
    size_t base = (((size_t)b*512 + 2*cp)*8 + (yy-1))*32 + (xi-1);
    v0 = feat[base];
    v1 = feat[base + 256];   // c+1 stride = 8*32
  }
  fT[idx] = packbf(v0, v1);
}

// ---------------- conv-weight transpose: Wf[a][c][t] -> wb[t][a][c] bf16 ----------------
__global__ __launch_bounds__(256) void k_tconv2(const float* __restrict__ Wf, uintT* __restrict__ wb){
  int idx = blockIdx.x*256 + threadIdx.x;  // 1,179,648 (grid 4608)
  int cp = idx & 255;
  int r  = idx >> 8;        // t*512 + a
  int a  = r & 511;
  int t  = r >> 9;
  float v0 = Wf[((size_t)a*512 + 2*cp)*9 + t];
  float v1 = Wf[((size_t)a*512 + 2*cp + 1)*9 + t];
  wb[idx] = packbf(v0, v1);
}

// ---------------- bf16 packers ----------------
__global__ __launch_bounds__(256) void k_wgate(const float* __restrict__ w0,
    const float* __restrict__ w1, const float* __restrict__ w2, uintT* __restrict__ o){
  int idx = blockIdx.x*256 + threadIdx.x;    // 1,572,864
  int m = idx >> 19, r = idx & 524287;
  const float* s = (m==0)? w0 : (m==1)? w1 : w2;
  float2 v = *(const float2*)(s + 2*(size_t)r);
  o[idx] = packbf(v.x, v.y);
}
__global__ __launch_bounds__(256) void k_woutb(const float* __restrict__ W, uintT* __restrict__ o){
  int idx = blockIdx.x*256 + threadIdx.x;    // 56,832
  float2 v = *(const float2*)(W + 2*(size_t)idx);
  o[idx] = packbf(v.x, v.y);
}
// WstT[u][ap] = pack(Wst[2ap][u], Wst[2ap+1][u])  (coalesced sp-GEMV layout)
__global__ __launch_bounds__(256) void k_wstT(const float* __restrict__ Wst, uintT* __restrict__ o){
  int idx = blockIdx.x*256 + threadIdx.x;    // 131,072
  int u = idx >> 8, ap = idx & 255;
  o[idx] = packbf(Wst[(size_t)(2*ap)*512 + u], Wst[(size_t)(2*ap+1)*512 + u]);
}

// ---------------- M0[j][g] = sum_k wih0[j][k]*Wemb[k][g] + bih0[j]+bhh0[j]; col 111 = bias-only ----------------
__global__ __launch_bounds__(128) void k_m0(const float* __restrict__ wih0,
                                            const float* __restrict__ Wemb,
                                            const float* __restrict__ bih0,
                                            const float* __restrict__ bhh0,
                                            float* __restrict__ M0){
  int j = blockIdx.x, g = threadIdx.x;
  float bs = bih0[j] + bhh0[j];
  if (g < V1){
    float acc = 0.f;
    const float* wr = wih0 + (size_t)j*512;
    for (int k=0;k<512;k++) acc += wr[k] * Wemb[(size_t)k*V1 + g];
    M0[(size_t)j*112 + g] = acc + bs;
  } else if (g == V1){
    M0[(size_t)j*112 + V1] = bs;
  }
}

// ---------------- MFMA conv (unchanged): 256 wgs, wg=(M 64 pos)x(N 256 a) ----------------
__global__ __launch_bounds__(256) void k_convm(const ushortT* __restrict__ fT,
                                               const ushortT* __restrict__ wb,
                                               const float* __restrict__ bfv,
                                               ushortT* __restrict__ fpj)
{
  __shared__ __align__(16) ushortT a_lds[136*72];
  __shared__ __align__(16) ushortT b_lds[256*72];
  const int tid = threadIdx.x;
  const int w   = tid >> 6;
  const int l   = tid & 63;
  const int kg  = l >> 4;
  const int ln  = l & 15;
  const int bid = blockIdx.x;
  const int nh  = bid & 1;
  const int mt  = bid >> 1;
  const int b   = mt >> 2;
  const int y0  = (mt & 3) * 2;
  const int a0  = nh * 256;

  f32x4 acc[4][4];
  #pragma unroll
  for (int nb=0; nb<4; nb++){
    float bv = bfv[a0 + w*64 + nb*16 + ln];
    #pragma unroll
    for (int mb=0; mb<4; mb++){
      acc[mb][nb][0]=bv; acc[mb][nb][1]=bv; acc[mb][nb][2]=bv; acc[mb][nb][3]=bv;
    }
  }

  const char* aSrc = (const char*)(fT + (((size_t)b*10 + y0)*34)*512);
  const char* wSrc = (const char*)wb;

  for (int c0 = 0; c0 < 512; c0 += 64){
    {
      const char* s = aSrc + (size_t)c0*2;
      #pragma unroll
      for (int i=0;i<4;i++){
        int idx = tid + i*256;
        int pos = idx >> 3, q = idx & 7;
        uint4 v = *(const uint4*)(s + (size_t)pos*1024 + q*16);
        *(uint4*)((char*)a_lds + pos*144 + q*16) = v;
      }
      if (tid < 64){
        int idx = 1024 + tid;
        int pos = idx >> 3, q = idx & 7;
        uint4 v = *(const uint4*)(s + (size_t)pos*1024 + q*16);
        *(uint4*)((char*)a_lds + pos*144 + q*16) = v;
      }
    }
    #pragma unroll
    for (int t=0; t<9; t++){
      const int ky = t/3, kx = t - (t/3)*3;
      {
        const char* s = wSrc + (((size_t)t*512 + a0)*512 + c0)*2;
        #pragma unroll
        for (int i=0;i<8;i++){
          int idx = tid + i*256;
          int ai = idx >> 3, q = idx & 7;
          uint4 v = *(const uint4*)(s + (size_t)ai*1024 + q*16);
          *(uint4*)((char*)b_lds + ai*144 + q*16) = v;
        }
      }
      __syncthreads();
      #pragma unroll
      for (int ks=0; ks<2; ks++){
        bf16x8 afr[4], bfr[4];
        #pragma unroll
        for (int mb=0; mb<4; mb++){
          int row = ((mb>>1) + ky)*34 + (mb&1)*16 + ln + kx;
          afr[mb] = *(const bf16x8*)((const char*)a_lds + row*144 + kg*16 + ks*64);
        }
        #pragma unroll
        for (int nb=0; nb<4; nb++){
          int ai = w*64 + nb*16 + ln;
          bfr[nb] = *(const bf16x8*)((const char*)b_lds + ai*144 + kg*16 + ks*64);
        }
        #pragma unroll
        for (int mb=0; mb<4; mb++)
          #pragma unroll
          for (int nb=0; nb<4; nb++)
            acc[mb][nb] = __builtin_amdgcn_mfma_f32_16x16x32_bf16(afr[mb], bfr[nb], acc[mb][nb], 0, 0, 0);
      }
      __syncthreads();
    }
  }

  #pragma unroll
  for (int mb=0; mb<4; mb++){
    #pragma unroll
    for (int nb=0; nb<4; nb++){
      int a = a0 + w*64 + nb*16 + ln;
      #pragma unroll
      for (int r4=0; r4<4; r4++){
        int pos = mb*16 + kg*4 + r4;
        fpj[((size_t)b*HWP + (y0*32 + pos))*512 + a] = f2b(acc[mb][nb][r4]);
      }
    }
  }
}

// ---------------- stage bf16 state [32 b][256 uints] MALL -> LDS [32][268] ----------------
__device__ __forceinline__ void stage_state_s(uintT* __restrict__ hs,
                                              const uintT* __restrict__ src, int tid){
  #pragma unroll
  for (int i=0;i<16;i++){
    int g = tid + i*512;
    hs[(g >> 8)*268 + (g & 255)] = sload_u(&src[g]);
  }
}

// ---------------- cumulative fence-free grid barrier (system scope) ----------------
__device__ __forceinline__ void sysbar(uintT* bar, int it, int bid){
  __syncthreads();   // vmcnt(0) drain: all block's system stores acked at MALL
  if (threadIdx.x == 0){
    __hip_atomic_fetch_add(bar + (bid & 7)*32, 1u, __ATOMIC_RELAXED, __HIP_MEMORY_SCOPE_SYSTEM);
    const uintT tgt = (uintT)(it + 1) * (uintT)NWG;
    for (;;){
      uintT s = 0;
      #pragma unroll
      for (int i=0;i<8;i++)
        s += __hip_atomic_load(bar + i*32, __ATOMIC_RELAXED, __HIP_MEMORY_SCOPE_SYSTEM);
      if (s >= tgt) break;
      __builtin_amdgcn_s_sleep(8);
    }
  }
  __syncthreads();
}

// ---------------- phase 1: persistent recurrence, 64 A + 64 B blocks ----------------
__global__ __launch_bounds__(512) void k_rec(
    const int* __restrict__ gt, const float* __restrict__ M0,
    const uintT* __restrict__ wgb,
    const float* __restrict__ bih1, const float* __restrict__ bhh1,
    float* __restrict__ st, uintT* __restrict__ h1hist, uintT* __restrict__ bar)
{
  __shared__ __align__(16) float pool[POOLF];
  const int tid = threadIdx.x, bid = blockIdx.x;
  uintT* h0bf = (uintT*)st;            // 2 parities x [32 b][256 u] bf16
  float* c0T  = st + 16384;            // [512][32] block-private
  float* c1T  = st + 32768;            // [512][32] block-private

  const bool isA = bid < 64;
  const int w   = tid >> 6;
  const int l   = tid & 63;
  const int kg  = l >> 4;
  const int ln  = l & 15;
  const int ks2 = w >> 2;
  const int rt  = (w >> 1) & 1;
  const int nh  = w & 1;
  const int u0  = (isA ? bid : bid - 64) * 8;
  const int jrow = (ln >> 2)*512 + u0 + rt*4 + (ln & 3);

  uint4 wA[8], wB1[8], wB2[8];
  if (isA){
    const uintT* wp = wgb + (size_t)jrow*256 + kg*4;            // whh0
    #pragma unroll
    for (int s8=0; s8<8; s8++) wA[s8] = *(const uint4*)(wp + (ks2*8 + s8)*16);
  } else {
    const uintT* wp1 = wgb + 524288  + (size_t)jrow*256 + kg*4; // wih1
    const uintT* wp2 = wgb + 1048576 + (size_t)jrow*256 + kg*4; // whh1
    #pragma unroll
    for (int s8=0; s8<8; s8++){
      wB1[s8] = *(const uint4*)(wp1 + (ks2*8 + s8)*16);
      wB2[s8] = *(const uint4*)(wp2 + (ks2*8 + s8)*16);
    }
  }

  uintT* hs = (uintT*)pool;          // [32][268] staged state
  float* gs = pool + 8576;           // [2][32][33] partial D
  float* hv = pool + 10688;          // [8][33] new h staging
  const ushortT* hb = (const ushortT*)hs + (nh*16 + ln)*536 + kg*8;

  for (int L = 0; L <= STEPS; L++){
    const int t = isA ? L : L - 1;
    if ((isA && t <= STEPS-1) || (!isA && t >= 0)){
      f32x4 acc = {0.f, 0.f, 0.f, 0.f};
      if (isA){
        stage_state_s(hs, h0bf + ((t+1)&1)*8192, tid);
        __syncthreads();
        #pragma unroll
        for (int s8=0; s8<8; s8++){
          int s = ks2*8 + s8;
          bf16x8 bfr = *(const bf16x8*)(hb + s*32);
          acc = __builtin_amdgcn_mfma_f32_16x16x32_bf16(u4_to_b8(wA[s8]), bfr, acc, 0, 0, 0);
        }
      } else {
        stage_state_s(hs, h0bf + (t&1)*8192, tid);
        __syncthreads();
        #pragma unroll
        for (int s8=0; s8<8; s8++){
          int s = ks2*8 + s8;
          bf16x8 bfr = *(const bf16x8*)(hb + s*32);
          acc = __builtin_amdgcn_mfma_f32_16x16x32_bf16(u4_to_b8(wB1[s8]), bfr, acc, 0, 0, 0);
        }
        __syncthreads();
        stage_state_s(hs, h1hist + (size_t)t*8192, tid);
        __syncthreads();
        #pragma unroll
        for (int s8=0; s8<8; s8++){
          int s = ks2*8 + s8;
          bf16x8 bfr = *(const bf16x8*)(hb + s*32);
          acc = __builtin_amdgcn_mfma_f32_16x16x32_bf16(u4_to_b8(wB2[s8]), bfr, acc, 0, 0, 0);
        }
      }
      #pragma unroll
      for (int r=0;r<4;r++)
        gs[(ks2*32 + kg*8 + rt*4 + r)*33 + nh*16 + ln] = acc[r];
      __syncthreads();

      if (tid < 256){
        const int ul = tid >> 5, b = tid & 31, u = u0 + ul;
        float g4[4];
        #pragma unroll
        for (int g=0; g<4; g++){
          float sacc = gs[(g*8+ul)*33 + b] + gs[(32 + g*8+ul)*33 + b];
          int j = g*512 + u;
          if (isA){
            int sym = (t > 0) ? gt[b*STEPS + t - 1] : V1;
            sacc += M0[(size_t)j*112 + sym];
          } else {
            sacc += bih1[j] + bhh1[j];
          }
          g4[g] = sacc;
        }
        float* cT = isA ? c0T : c1T;
        int idx = u*32 + b;
        float cn = sigf(g4[1])*cT[idx] + sigf(g4[0])*tanh_f(g4[2]);
        cT[idx] = cn;                               // block-private, plain
        float h = sigf(g4[3])*tanh_f(cn);
        hv[ul*33 + b] = h;
      }
      __syncthreads();
      if (tid < 128){
        const int up = tid >> 5, b = tid & 31;
        uintT v = packbf(hv[(up*2)*33 + b], hv[(up*2+1)*33 + b]);
        if (isA) sstore_u(&h0bf[(t&1)*8192 + b*256 + (u0>>1) + up], v);
        else     sstore_u(&h1hist[(size_t)(t+1)*8192 + b*256 + (u0>>1) + up], v);
      }
    }
    if (L < STEPS) sysbar(bar, L, bid);
  }
}

// ---------------- phase 2: attention for all (b, r) in parallel (992 blocks) ----------------
__global__ __launch_bounds__(512) void k_att(
    const float* __restrict__ features, const uintT* __restrict__ h1hist,
    const ushortT* __restrict__ fpj, const uintT* __restrict__ WstTb,
    const float* __restrict__ watt, const uintT* __restrict__ Woutb,
    const float* __restrict__ bout, float* __restrict__ out)
{
  __shared__ __align__(16) float pool[7488];
  const int tid = threadIdx.x;
  const int b = blockIdx.x / STEPS, r = blockIdx.x % STEPS;
  float* h1s   = pool;            // 512
  float* spsl  = pool + 512;      // 512
  float* watts = pool + 1024;     // 512
  float* pals  = pool + 1536;     // 512
  float* attw  = pool + 2048;     // 256
  float* glim  = pool + 2304;     // 512
  float* red   = pool + 2816;     // 64
  float* opart = pool + 2880;     // 512
  float* sppt  = pool + 3392;     // 4096 (8 uq x 512 a)

  if (tid < 256){
    uintT hvw = h1hist[(size_t)(r+1)*8192 + b*256 + tid];  // h1(r)
    h1s[2*tid]   = blo(hvw);
    h1s[2*tid+1] = bhi(hvw);
  }
  watts[tid] = watt[tid];
  __syncthreads();

  // sp partials: 8 u-ranges x 512 a; uint4 weight loads (64/thread)
  {
    int ap4 = tid & 63, uq = tid >> 6;
    float a8[8] = {0.f,0.f,0.f,0.f,0.f,0.f,0.f,0.f};
    const uint4* wp = (const uint4*)(WstTb + (size_t)(uq*64)*256) + ap4;
    const float* hq = h1s + uq*64;
    #pragma unroll 8
    for (int u=0; u<64; u++){
      uint4 q = wp[(size_t)u*64];
      float h = hq[u];
      a8[0] += blo(q.x)*h; a8[1] += bhi(q.x)*h;
      a8[2] += blo(q.y)*h; a8[3] += bhi(q.y)*h;
      a8[4] += blo(q.z)*h; a8[5] += bhi(q.z)*h;
      a8[6] += blo(q.w)*h; a8[7] += bhi(q.w)*h;
    }
    #pragma unroll
    for (int j=0;j<8;j++) sppt[uq*512 + ap4*8 + j] = a8[j];
  }
  __syncthreads();
  {
    float s = 0.f;
    #pragma unroll
    for (int uq=0;uq<8;uq++) s += sppt[uq*512 + tid];
    spsl[tid] = s;
  }
  __syncthreads();

  // attention logits over (p, a-half)
  {
    int p = tid & 255, ac = tid >> 8;
    const uint4* fr = (const uint4*)(fpj + ((size_t)b*HWP + p)*512 + ac*256);
    float al2 = 0.f;
    #pragma unroll 8
    for (int kb=0;kb<32;kb++){
      uint4 q = fr[kb];
      float v[8] = {blo(q.x),bhi(q.x),blo(q.y),bhi(q.y),blo(q.z),bhi(q.z),blo(q.w),bhi(q.w)};
      int a0 = ac*256 + kb*8;
      #pragma unroll
      for (int i=0;i<8;i++)
        al2 += watts[a0+i] * tanh_f(v[i] + spsl[a0+i]);
    }
    pals[tid] = al2;
  }
  __syncthreads();
  // softmax over 256 positions
  {
    float al2 = (tid < 256) ? (pals[tid] + pals[256+tid]) : -1e30f;
    float m = al2;
    #pragma unroll
    for (int off=32; off>0; off>>=1) m = fmaxf(m, __shfl_xor(m, off));
    if (tid < 256 && (tid & 63)==0) red[tid>>6] = m;
    __syncthreads();
    m = fmaxf(fmaxf(red[0],red[1]), fmaxf(red[2],red[3]));
    float e = (tid < 256) ? __expf(al2 - m) : 0.f;
    float s = e;
    #pragma unroll
    for (int off=32; off>0; off>>=1) s += __shfl_xor(s, off);
    __syncthreads();
    if (tid < 256 && (tid & 63)==0) red[tid>>6] = s;
    __syncthreads();
    if (tid < 256){
      float sa = red[0]+red[1]+red[2]+red[3];
      attw[tid] = e / sa;
    }
  }
  __syncthreads();
  // glimpse[c] = sum_p features[b,c,p] * attw[p]  (f32 direct)
  {
    const float4* fr = (const float4*)(features + ((size_t)b*512 + tid)*256);
    float acc = 0.f;
    #pragma unroll 8
    for (int kb=0;kb<64;kb++){
      float4 v = fr[kb];
      const float* aw = attw + kb*4;
      acc += v.x*aw[0] + v.y*aw[1] + v.z*aw[2] + v.w*aw[3];
    }
    glim[tid] = acc;
  }
  __syncthreads();
  // logits = [h1, glimpse] @ Wout^T + b_out; 4x parallel over k-quarters
  {
    int q = tid >> 7, o = tid & 127;
    float acc = 0.f;
    if (o < V1){
      const uint4* wr4 = (const uint4*)(Woutb + (size_t)o*512 + q*128);
      const float* src = (q < 2) ? (h1s + q*256) : (glim + (q-2)*256);
      #pragma unroll 8
      for (int kb=0;kb<32;kb++){
        uint4 w4 = wr4[kb];
        const float* sx = src + kb*8;
        acc += blo(w4.x)*sx[0] + bhi(w4.x)*sx[1] + blo(w4.y)*sx[2] + bhi(w4.y)*sx[3]
             + blo(w4.z)*sx[4] + bhi(w4.z)*sx[5] + blo(w4.w)*sx[6] + bhi(w4.w)*sx[7];
      }
    }
    opart[tid] = acc;
  }
  __syncthreads();
  if (tid < V1){
    float acc = bout[tid] + opart[tid] + opart[128+tid] + opart[256+tid] + opart[384+tid];
    out[(size_t)b*STEPS*V1 + (size_t)r*V1 + tid] = acc;
  }
}

extern "C" void kernel_launch(void* const* d_in, const int* in_sizes, int n_in,
                              void* d_out, int out_size, void* d_ws, size_t ws_size,
                              hipStream_t stream)
{
  const float* features = (const float*)d_in[0];
  const int*   gt       = (const int*)d_in[2];
  const float* Wf    = (const float*)d_in[3];
  const float* bfv   = (const float*)d_in[4];
  const float* Wst   = (const float*)d_in[5];
  const float* watt  = (const float*)d_in[6];
  const float* Wemb  = (const float*)d_in[7];
  const float* wih0  = (const float*)d_in[8];
  const float* whh0  = (const float*)d_in[9];
  const float* bih0  = (const float*)d_in[10];
  const float* bhh0  = (const float*)d_in[11];
  const float* wih1  = (const float*)d_in[12];
  const float* whh1  = (const float*)d_in[13];
  const float* bih1  = (const float*)d_in[14];
  const float* bhh1  = (const float*)d_in[15];
  const float* Wout  = (const float*)d_in[16];
  const float* bout  = (const float*)d_in[17];
  float* out = (float*)d_out;

  // ---- workspace layout (bytes), max extent 25,133,056 (proven footprint) ----
  char* wsb = (char*)d_ws;
  ushortT* fpj    = (ushortT*)(wsb + 0);          //  8,388,608 persist
  uintT*   h1hist = (uintT*)  (wsb + 8388608);    //  1,048,576 (32 slots x 32KB; slot0 = zeros)
  float*   M0     = (float*)  (wsb + 16777216);   //    917,504 (incl. bias col 111)
  uintT*   wgb    = (uintT*)  (wsb + 17694720);   //  6,291,456 (whh0|wih1|whh1 bf16)
  uintT*   Woutb  = (uintT*)  (wsb + 23986176);   //    227,328 (ends 24,213,504)
  uintT*   bar    = (uintT*)  (wsb + 24213504);   //      1,024 (8 counters x 128B)
  uintT*   WstTb  = (uintT*)  (wsb + 24215552);   //    524,288
  float*   st     = (float*)  (wsb + 24739840);   //    196,608 (h0bf x2, c0, c1)
  // transients (dead after k_convm; overlay h1hist/M0/wgb/Woutb/bar/WstTb):
  uintT*   fTt    = (uintT*)  (wsb + 8388608);    // 11,141,120 bf16 featTp
  ushortT* wbt    = (ushortT*)(wsb + 19529728);   //  4,718,592 bf16 wb[t][a][c] (ends 24,248,320)

  k_featT <<<10880, 256, 0, stream>>>(features, fTt);
  k_tconv2<<<4608,  256, 0, stream>>>(Wf, (uintT*)wbt);
  k_convm <<<256,   256, 0, stream>>>((const ushortT*)fTt, wbt, bfv, fpj);
  // everything below overlays conv transients -> must run AFTER k_convm
  k_init  <<<225,   256, 0, stream>>>(st, h1hist, bar);
  k_wgate <<<6144,  256, 0, stream>>>(whh0, wih1, whh1, wgb);
  k_wstT  <<<512,   256, 0, stream>>>(Wst, WstTb);
  k_woutb <<<222,   256, 0, stream>>>(Wout, Woutb);
  k_m0    <<<2048,  128, 0, stream>>>(wih0, Wemb, bih0, bhh0, M0);

  {
    void* args[] = {
      (void*)&gt, (void*)&M0, (void*)&wgb, (void*)&bih1, (void*)&bhh1,
      (void*)&st, (void*)&h1hist, (void*)&bar
    };
    // cooperative launch for the co-residency guarantee; sync is our own
    hipLaunchCooperativeKernel((const void*)k_rec, dim3(NWG), dim3(512),
                               args, 0, stream);
  }
  k_att <<<32*STEPS, 512, 0, stream>>>(features, h1hist, fpj, WstTb, watt,
                                       Woutb, bout, out);
  (void)in_sizes; (void)n_in; (void)out_size; (void)ws_size;
}

// Round 7
// 756.725 us; speedup vs baseline: 3.0595x; 1.0567x over previous
//
#include <hip/hip_runtime.h>
#include <hip/hip_bf16.h>

// SARDecoder round 15: launch-machinery pass; kernel bodies byte-identical to
// the r14-verified versions. (1) k_rec -> REGULAR launch: coop launch likely
// broke graph capture (~280us of time outside kernel bodies); co-residency of
// 128 blocks <= 256 CUs with 44KB LDS is physically guaranteed, and sync is
// our own system-scope sysbar (verified r14), not grid.sync. (2) 10 launches
// -> 5: k_pre = featT+tconv2; k_post = wgate+wstT+woutb+m0(256t)+init.

#define RNN   512
#define V1    111
#define STEPS 31
#define HWP   256
#define POOLF 11008
#define NWG   128

typedef unsigned short ushortT;
typedef unsigned int   uintT;
typedef __attribute__((ext_vector_type(8))) short bf16x8;   // 8 bf16 (4 VGPRs)
typedef __attribute__((ext_vector_type(4))) float f32x4;

__device__ __forceinline__ float blo(uintT u){ union { uintT i; float f; } v; v.i = u << 16; return v.f; }
__device__ __forceinline__ float bhi(uintT u){ union { uintT i; float f; } v; v.i = u & 0xffff0000u; return v.f; }
__device__ __forceinline__ ushortT f2b(float f){
  __hip_bfloat16 h = __float2bfloat16(f);
  union { __hip_bfloat16 b; ushortT s; } v; v.b = h; return v.s;
}
__device__ __forceinline__ uintT packbf(float lo, float hi){
  return (uintT)f2b(lo) | ((uintT)f2b(hi) << 16);
}
__device__ __forceinline__ bf16x8 u4_to_b8(uint4 u){
  union { uint4 a; bf16x8 b; } v; v.a = u; return v.b;
}
__device__ __forceinline__ float sigf(float x){ return 1.f/(1.f + __expf(-x)); }
__device__ __forceinline__ float tanh_f(float x){ float e = __expf(2.f*x); return 1.f - 2.f/(e+1.f); }

// ---- SYSTEM-scope relaxed atomics: bypass L2 both directions (MALL-coherent) ----
__device__ __forceinline__ uintT sload_u(const uintT* p){
  return __hip_atomic_load((uintT*)p, __ATOMIC_RELAXED, __HIP_MEMORY_SCOPE_SYSTEM);
}
__device__ __forceinline__ void sstore_u(uintT* p, uintT v){
  __hip_atomic_store(p, v, __ATOMIC_RELAXED, __HIP_MEMORY_SCOPE_SYSTEM);
}

// ---------------- k_pre: featT (bid<10880) + tconv2 (grid 15488) ----------------
__global__ __launch_bounds__(256) void k_pre(const float* __restrict__ feat,
                                             const float* __restrict__ Wf,
                                             uintT* __restrict__ fT,
                                             uintT* __restrict__ wb){
  const int bid = blockIdx.x, tid = threadIdx.x;
  if (bid < 10880){
    // features fp32 [b][c][y][x] -> bf16 [b][yy0..9][xi0..33][c], zero halo
    int idx = bid*256 + tid;
    int cp = idx & 255;
    int r  = idx >> 8;
    int xi = r % 34;
    int q  = r / 34;
    int yy = q % 10;
    int b  = q / 10;
    float v0 = 0.f, v1 = 0.f;
    if (yy >= 1 && yy <= 8 && xi >= 1 && xi <= 32){
      size_t base = (((size_t)b*512 + 2*cp)*8 + (yy-1))*32 + (xi-1);
      v0 = feat[base];
      v1 = feat[base + 256];
    }
    fT[idx] = packbf(v0, v1);
  } else {
    // Wf[a][c][t] -> wb[t][a][c] bf16
    int idx = (bid - 10880)*256 + tid;   // 1,179,648
    int cp = idx & 255;
    int r  = idx >> 8;
    int a  = r & 511;
    int t  = r >> 9;
    float v0 = Wf[((size_t)a*512 + 2*cp)*9 + t];
    float v1 = Wf[((size_t)a*512 + 2*cp + 1)*9 + t];
    wb[idx] = packbf(v0, v1);
  }
}

// ---------------- k_post: wgate | wstT | woutb | m0 | init (grid 8127) ----------------
__global__ __launch_bounds__(256) void k_post(
    const float* __restrict__ w0, const float* __restrict__ w1,
    const float* __restrict__ w2, uintT* __restrict__ wgb,
    const float* __restrict__ Wst, uintT* __restrict__ WstTb,
    const float* __restrict__ Wout, uintT* __restrict__ Woutb,
    const float* __restrict__ wih0, const float* __restrict__ Wemb,
    const float* __restrict__ bih0, const float* __restrict__ bhh0,
    float* __restrict__ M0,
    float* __restrict__ st, uintT* __restrict__ h1hist, uintT* __restrict__ bar)
{
  const int bid = blockIdx.x, tid = threadIdx.x;
  if (bid < 6144){
    int idx = bid*256 + tid;            // 1,572,864
    int m = idx >> 19, r = idx & 524287;
    const float* s = (m==0)? w0 : (m==1)? w1 : w2;
    float2 v = *(const float2*)(s + 2*(size_t)r);
    wgb[idx] = packbf(v.x, v.y);
  } else if (bid < 6656){
    int idx = (bid-6144)*256 + tid;     // 131,072
    int u = idx >> 8, ap = idx & 255;
    WstTb[idx] = packbf(Wst[(size_t)(2*ap)*512 + u], Wst[(size_t)(2*ap+1)*512 + u]);
  } else if (bid < 6878){
    int idx = (bid-6656)*256 + tid;     // 56,832
    float2 v = *(const float2*)(Wout + 2*(size_t)idx);
    Woutb[idx] = packbf(v.x, v.y);
  } else if (bid < 7902){
    int j = (bid-6878)*2 + (tid >> 7);  // 2048 rows
    int g = tid & 127;
    float bs = bih0[j] + bhh0[j];
    if (g < V1){
      float acc = 0.f;
      const float* wr = wih0 + (size_t)j*512;
      for (int k=0;k<512;k++) acc += wr[k] * Wemb[(size_t)k*V1 + g];
      M0[(size_t)j*112 + g] = acc + bs;
    } else if (g == V1){
      M0[(size_t)j*112 + V1] = bs;
    }
  } else {
    int b2 = bid - 7902;                // 225 blocks
    if (b2 < 192)      st[b2*256 + tid] = 0.f;
    else if (b2 < 224) h1hist[(b2-192)*256 + tid] = 0u;
    else if (tid < 8)  bar[tid*32] = 0u;
  }
}

// ---------------- MFMA conv (unchanged): 256 wgs, wg=(M 64 pos)x(N 256 a) ----------------
__global__ __launch_bounds__(256) void k_convm(const ushortT* __restrict__ fT,
                                               const ushortT* __restrict__ wb,
                                               const float* __restrict__ bfv,
                                               ushortT* __restrict__ fpj)
{
  __shared__ __align__(16) ushortT a_lds[136*72];
  __shared__ __align__(16) ushortT b_lds[256*72];
  const int tid = threadIdx.x;
  const int w   = tid >> 6;
  const int l   = tid & 63;
  const int kg  = l >> 4;
  const int ln  = l & 15;
  const int bid = blockIdx.x;
  const int nh  = bid & 1;
  const int mt  = bid >> 1;
  const int b   = mt >> 2;
  const int y0  = (mt & 3) * 2;
  const int a0  = nh * 256;

  f32x4 acc[4][4];
  #pragma unroll
  for (int nb=0; nb<4; nb++){
    float bv = bfv[a0 + w*64 + nb*16 + ln];
    #pragma unroll
    for (int mb=0; mb<4; mb++){
      acc[mb][nb][0]=bv; acc[mb][nb][1]=bv; acc[mb][nb][2]=bv; acc[mb][nb][3]=bv;
    }
  }

  const char* aSrc = (const char*)(fT + (((size_t)b*10 + y0)*34)*512);
  const char* wSrc = (const char*)wb;

  for (int c0 = 0; c0 < 512; c0 += 64){
    {
      const char* s = aSrc + (size_t)c0*2;
      #pragma unroll
      for (int i=0;i<4;i++){
        int idx = tid + i*256;
        int pos = idx >> 3, q = idx & 7;
        uint4 v = *(const uint4*)(s + (size_t)pos*1024 + q*16);
        *(uint4*)((char*)a_lds + pos*144 + q*16) = v;
      }
      if (tid < 64){
        int idx = 1024 + tid;
        int pos = idx >> 3, q = idx & 7;
        uint4 v = *(const uint4*)(s + (size_t)pos*1024 + q*16);
        *(uint4*)((char*)a_lds + pos*144 + q*16) = v;
      }
    }
    #pragma unroll
    for (int t=0; t<9; t++){
      const int ky = t/3, kx = t - (t/3)*3;
      {
        const char* s = wSrc + (((size_t)t*512 + a0)*512 + c0)*2;
        #pragma unroll
        for (int i=0;i<8;i++){
          int idx = tid + i*256;
          int ai = idx >> 3, q = idx & 7;
          uint4 v = *(const uint4*)(s + (size_t)ai*1024 + q*16);
          *(uint4*)((char*)b_lds + ai*144 + q*16) = v;
        }
      }
      __syncthreads();
      #pragma unroll
      for (int ks=0; ks<2; ks++){
        bf16x8 afr[4], bfr[4];
        #pragma unroll
        for (int mb=0; mb<4; mb++){
          int row = ((mb>>1) + ky)*34 + (mb&1)*16 + ln + kx;
          afr[mb] = *(const bf16x8*)((const char*)a_lds + row*144 + kg*16 + ks*64);
        }
        #pragma unroll
        for (int nb=0; nb<4; nb++){
          int ai = w*64 + nb*16 + ln;
          bfr[nb] = *(const bf16x8*)((const char*)b_lds + ai*144 + kg*16 + ks*64);
        }
        #pragma unroll
        for (int mb=0; mb<4; mb++)
          #pragma unroll
          for (int nb=0; nb<4; nb++)
            acc[mb][nb] = __builtin_amdgcn_mfma_f32_16x16x32_bf16(afr[mb], bfr[nb], acc[mb][nb], 0, 0, 0);
      }
      __syncthreads();
    }
  }

  #pragma unroll
  for (int mb=0; mb<4; mb++){
    #pragma unroll
    for (int nb=0; nb<4; nb++){
      int a = a0 + w*64 + nb*16 + ln;
      #pragma unroll
      for (int r4=0; r4<4; r4++){
        int pos = mb*16 + kg*4 + r4;
        fpj[((size_t)b*HWP + (y0*32 + pos))*512 + a] = f2b(acc[mb][nb][r4]);
      }
    }
  }
}

// ---------------- stage bf16 state [32 b][256 uints] MALL -> LDS [32][268] ----------------
__device__ __forceinline__ void stage_state_s(uintT* __restrict__ hs,
                                              const uintT* __restrict__ src, int tid){
  #pragma unroll
  for (int i=0;i<16;i++){
    int g = tid + i*512;
    hs[(g >> 8)*268 + (g & 255)] = sload_u(&src[g]);
  }
}

// ---------------- cumulative fence-free grid barrier (system scope) ----------------
__device__ __forceinline__ void sysbar(uintT* bar, int it, int bid){
  __syncthreads();   // vmcnt(0) drain: all block's system stores acked at MALL
  if (threadIdx.x == 0){
    __hip_atomic_fetch_add(bar + (bid & 7)*32, 1u, __ATOMIC_RELAXED, __HIP_MEMORY_SCOPE_SYSTEM);
    const uintT tgt = (uintT)(it + 1) * (uintT)NWG;
    for (;;){
      uintT s = 0;
      #pragma unroll
      for (int i=0;i<8;i++)
        s += __hip_atomic_load(bar + i*32, __ATOMIC_RELAXED, __HIP_MEMORY_SCOPE_SYSTEM);
      if (s >= tgt) break;
      __builtin_amdgcn_s_sleep(8);
    }
  }
  __syncthreads();
}

// ---------------- phase 1: persistent recurrence, 64 A + 64 B blocks ----------------
__global__ __launch_bounds__(512) void k_rec(
    const int* __restrict__ gt, const float* __restrict__ M0,
    const uintT* __restrict__ wgb,
    const float* __restrict__ bih1, const float* __restrict__ bhh1,
    float* __restrict__ st, uintT* __restrict__ h1hist, uintT* __restrict__ bar)
{
  __shared__ __align__(16) float pool[POOLF];
  const int tid = threadIdx.x, bid = blockIdx.x;
  uintT* h0bf = (uintT*)st;            // 2 parities x [32 b][256 u] bf16
  float* c0T  = st + 16384;            // [512][32] block-private
  float* c1T  = st + 32768;            // [512][32] block-private

  const bool isA = bid < 64;
  const int w   = tid >> 6;
  const int l   = tid & 63;
  const int kg  = l >> 4;
  const int ln  = l & 15;
  const int ks2 = w >> 2;
  const int rt  = (w >> 1) & 1;
  const int nh  = w & 1;
  const int u0  = (isA ? bid : bid - 64) * 8;
  const int jrow = (ln >> 2)*512 + u0 + rt*4 + (ln & 3);

  uint4 wA[8], wB1[8], wB2[8];
  if (isA){
    const uintT* wp = wgb + (size_t)jrow*256 + kg*4;            // whh0
    #pragma unroll
    for (int s8=0; s8<8; s8++) wA[s8] = *(const uint4*)(wp + (ks2*8 + s8)*16);
  } else {
    const uintT* wp1 = wgb + 524288  + (size_t)jrow*256 + kg*4; // wih1
    const uintT* wp2 = wgb + 1048576 + (size_t)jrow*256 + kg*4; // whh1
    #pragma unroll
    for (int s8=0; s8<8; s8++){
      wB1[s8] = *(const uint4*)(wp1 + (ks2*8 + s8)*16);
      wB2[s8] = *(const uint4*)(wp2 + (ks2*8 + s8)*16);
    }
  }

  uintT* hs = (uintT*)pool;          // [32][268] staged state
  float* gs = pool + 8576;           // [2][32][33] partial D
  float* hv = pool + 10688;          // [8][33] new h staging
  const ushortT* hb = (const ushortT*)hs + (nh*16 + ln)*536 + kg*8;

  for (int L = 0; L <= STEPS; L++){
    const int t = isA ? L : L - 1;
    if ((isA && t <= STEPS-1) || (!isA && t >= 0)){
      f32x4 acc = {0.f, 0.f, 0.f, 0.f};
      if (isA){
        stage_state_s(hs, h0bf + ((t+1)&1)*8192, tid);
        __syncthreads();
        #pragma unroll
        for (int s8=0; s8<8; s8++){
          int s = ks2*8 + s8;
          bf16x8 bfr = *(const bf16x8*)(hb + s*32);
          acc = __builtin_amdgcn_mfma_f32_16x16x32_bf16(u4_to_b8(wA[s8]), bfr, acc, 0, 0, 0);
        }
      } else {
        stage_state_s(hs, h0bf + (t&1)*8192, tid);
        __syncthreads();
        #pragma unroll
        for (int s8=0; s8<8; s8++){
          int s = ks2*8 + s8;
          bf16x8 bfr = *(const bf16x8*)(hb + s*32);
          acc = __builtin_amdgcn_mfma_f32_16x16x32_bf16(u4_to_b8(wB1[s8]), bfr, acc, 0, 0, 0);
        }
        __syncthreads();
        stage_state_s(hs, h1hist + (size_t)t*8192, tid);
        __syncthreads();
        #pragma unroll
        for (int s8=0; s8<8; s8++){
          int s = ks2*8 + s8;
          bf16x8 bfr = *(const bf16x8*)(hb + s*32);
          acc = __builtin_amdgcn_mfma_f32_16x16x32_bf16(u4_to_b8(wB2[s8]), bfr, acc, 0, 0, 0);
        }
      }
      #pragma unroll
      for (int r=0;r<4;r++)
        gs[(ks2*32 + kg*8 + rt*4 + r)*33 + nh*16 + ln] = acc[r];
      __syncthreads();

      if (tid < 256){
        const int ul = tid >> 5, b = tid & 31, u = u0 + ul;
        float g4[4];
        #pragma unroll
        for (int g=0; g<4; g++){
          float sacc = gs[(g*8+ul)*33 + b] + gs[(32 + g*8+ul)*33 + b];
          int j = g*512 + u;
          if (isA){
            int sym = (t > 0) ? gt[b*STEPS + t - 1] : V1;
            sacc += M0[(size_t)j*112 + sym];
          } else {
            sacc += bih1[j] + bhh1[j];
          }
          g4[g] = sacc;
        }
        float* cT = isA ? c0T : c1T;
        int idx = u*32 + b;
        float cn = sigf(g4[1])*cT[idx] + sigf(g4[0])*tanh_f(g4[2]);
        cT[idx] = cn;                               // block-private, plain
        float h = sigf(g4[3])*tanh_f(cn);
        hv[ul*33 + b] = h;
      }
      __syncthreads();
      if (tid < 128){
        const int up = tid >> 5, b = tid & 31;
        uintT v = packbf(hv[(up*2)*33 + b], hv[(up*2+1)*33 + b]);
        if (isA) sstore_u(&h0bf[(t&1)*8192 + b*256 + (u0>>1) + up], v);
        else     sstore_u(&h1hist[(size_t)(t+1)*8192 + b*256 + (u0>>1) + up], v);
      }
    }
    if (L < STEPS) sysbar(bar, L, bid);
  }
}

// ---------------- phase 2: attention for all (b, r) in parallel (992 blocks) ----------------
__global__ __launch_bounds__(512) void k_att(
    const float* __restrict__ features, const uintT* __restrict__ h1hist,
    const ushortT* __restrict__ fpj, const uintT* __restrict__ WstTb,
    const float* __restrict__ watt, const uintT* __restrict__ Woutb,
    const float* __restrict__ bout, float* __restrict__ out)
{
  __shared__ __align__(16) float pool[7488];
  const int tid = threadIdx.x;
  const int b = blockIdx.x / STEPS, r = blockIdx.x % STEPS;
  float* h1s   = pool;            // 512
  float* spsl  = pool + 512;      // 512
  float* watts = pool + 1024;     // 512
  float* pals  = pool + 1536;     // 512
  float* attw  = pool + 2048;     // 256
  float* glim  = pool + 2304;     // 512
  float* red   = pool + 2816;     // 64
  float* opart = pool + 2880;     // 512
  float* sppt  = pool + 3392;     // 4096 (8 uq x 512 a)

  if (tid < 256){
    uintT hvw = h1hist[(size_t)(r+1)*8192 + b*256 + tid];  // h1(r)
    h1s[2*tid]   = blo(hvw);
    h1s[2*tid+1] = bhi(hvw);
  }
  watts[tid] = watt[tid];
  __syncthreads();

  // sp partials: 8 u-ranges x 512 a; uint4 weight loads (64/thread)
  {
    int ap4 = tid & 63, uq = tid >> 6;
    float a8[8] = {0.f,0.f,0.f,0.f,0.f,0.f,0.f,0.f};
    const uint4* wp = (const uint4*)(WstTb + (size_t)(uq*64)*256) + ap4;
    const float* hq = h1s + uq*64;
    #pragma unroll 8
    for (int u=0; u<64; u++){
      uint4 q = wp[(size_t)u*64];
      float h = hq[u];
      a8[0] += blo(q.x)*h; a8[1] += bhi(q.x)*h;
      a8[2] += blo(q.y)*h; a8[3] += bhi(q.y)*h;
      a8[4] += blo(q.z)*h; a8[5] += bhi(q.z)*h;
      a8[6] += blo(q.w)*h; a8[7] += bhi(q.w)*h;
    }
    #pragma unroll
    for (int j=0;j<8;j++) sppt[uq*512 + ap4*8 + j] = a8[j];
  }
  __syncthreads();
  {
    float s = 0.f;
    #pragma unroll
    for (int uq=0;uq<8;uq++) s += sppt[uq*512 + tid];
    spsl[tid] = s;
  }
  __syncthreads();

  // attention logits over (p, a-half)
  {
    int p = tid & 255, ac = tid >> 8;
    const uint4* fr = (const uint4*)(fpj + ((size_t)b*HWP + p)*512 + ac*256);
    float al2 = 0.f;
    #pragma unroll 8
    for (int kb=0;kb<32;kb++){
      uint4 q = fr[kb];
      float v[8] = {blo(q.x),bhi(q.x),blo(q.y),bhi(q.y),blo(q.z),bhi(q.z),blo(q.w),bhi(q.w)};
      int a0 = ac*256 + kb*8;
      #pragma unroll
      for (int i=0;i<8;i++)
        al2 += watts[a0+i] * tanh_f(v[i] + spsl[a0+i]);
    }
    pals[tid] = al2;
  }
  __syncthreads();
  // softmax over 256 positions
  {
    float al2 = (tid < 256) ? (pals[tid] + pals[256+tid]) : -1e30f;
    float m = al2;
    #pragma unroll
    for (int off=32; off>0; off>>=1) m = fmaxf(m, __shfl_xor(m, off));
    if (tid < 256 && (tid & 63)==0) red[tid>>6] = m;
    __syncthreads();
    m = fmaxf(fmaxf(red[0],red[1]), fmaxf(red[2],red[3]));
    float e = (tid < 256) ? __expf(al2 - m) : 0.f;
    float s = e;
    #pragma unroll
    for (int off=32; off>0; off>>=1) s += __shfl_xor(s, off);
    __syncthreads();
    if (tid < 256 && (tid & 63)==0) red[tid>>6] = s;
    __syncthreads();
    if (tid < 256){
      float sa = red[0]+red[1]+red[2]+red[3];
      attw[tid] = e / sa;
    }
  }
  __syncthreads();
  // glimpse[c] = sum_p features[b,c,p] * attw[p]  (f32 direct)
  {
    const float4* fr = (const float4*)(features + ((size_t)b*512 + tid)*256);
    float acc = 0.f;
    #pragma unroll 8
    for (int kb=0;kb<64;kb++){
      float4 v = fr[kb];
      const float* aw = attw + kb*4;
      acc += v.x*aw[0] + v.y*aw[1] + v.z*aw[2] + v.w*aw[3];
    }
    glim[tid] = acc;
  }
  __syncthreads();
  // logits = [h1, glimpse] @ Wout^T + b_out; 4x parallel over k-quarters
  {
    int q = tid >> 7, o = tid & 127;
    float acc = 0.f;
    if (o < V1){
      const uint4* wr4 = (const uint4*)(Woutb + (size_t)o*512 + q*128);
      const float* src = (q < 2) ? (h1s + q*256) : (glim + (q-2)*256);
      #pragma unroll 8
      for (int kb=0;kb<32;kb++){
        uint4 w4 = wr4[kb];
        const float* sx = src + kb*8;
        acc += blo(w4.x)*sx[0] + bhi(w4.x)*sx[1] + blo(w4.y)*sx[2] + bhi(w4.y)*sx[3]
             + blo(w4.z)*sx[4] + bhi(w4.z)*sx[5] + blo(w4.w)*sx[6] + bhi(w4.w)*sx[7];
      }
    }
    opart[tid] = acc;
  }
  __syncthreads();
  if (tid < V1){
    float acc = bout[tid] + opart[tid] + opart[128+tid] + opart[256+tid] + opart[384+tid];
    out[(size_t)b*STEPS*V1 + (size_t)r*V1 + tid] = acc;
  }
}

extern "C" void kernel_launch(void* const* d_in, const int* in_sizes, int n_in,
                              void* d_out, int out_size, void* d_ws, size_t ws_size,
                              hipStream_t stream)
{
  const float* features = (const float*)d_in[0];
  const int*   gt       = (const int*)d_in[2];
  const float* Wf    = (const float*)d_in[3];
  const float* bfv   = (const float*)d_in[4];
  const float* Wst   = (const float*)d_in[5];
  const float* watt  = (const float*)d_in[6];
  const float* Wemb  = (const float*)d_in[7];
  const float* wih0  = (const float*)d_in[8];
  const float* whh0  = (const float*)d_in[9];
  const float* bih0  = (const float*)d_in[10];
  const float* bhh0  = (const float*)d_in[11];
  const float* wih1  = (const float*)d_in[12];
  const float* whh1  = (const float*)d_in[13];
  const float* bih1  = (const float*)d_in[14];
  const float* bhh1  = (const float*)d_in[15];
  const float* Wout  = (const float*)d_in[16];
  const float* bout  = (const float*)d_in[17];
  float* out = (float*)d_out;

  // ---- workspace layout (bytes), max extent 25,133,056 (proven footprint) ----
  char* wsb = (char*)d_ws;
  ushortT* fpj    = (ushortT*)(wsb + 0);          //  8,388,608 persist
  uintT*   h1hist = (uintT*)  (wsb + 8388608);    //  1,048,576 (32 slots x 32KB; slot0 = zeros)
  float*   M0     = (float*)  (wsb + 16777216);   //    917,504 (incl. bias col 111)
  uintT*   wgb    = (uintT*)  (wsb + 17694720);   //  6,291,456 (whh0|wih1|whh1 bf16)
  uintT*   Woutb  = (uintT*)  (wsb + 23986176);   //    227,328 (ends 24,213,504)
  uintT*   bar    = (uintT*)  (wsb + 24213504);   //      1,024 (8 counters x 128B)
  uintT*   WstTb  = (uintT*)  (wsb + 24215552);   //    524,288
  float*   st     = (float*)  (wsb + 24739840);   //    196,608 (h0bf x2, c0, c1)
  // transients (dead after k_convm; overlay h1hist/M0/wgb/Woutb/bar/WstTb):
  uintT*   fTt    = (uintT*)  (wsb + 8388608);    // 11,141,120 bf16 featTp
  ushortT* wbt    = (ushortT*)(wsb + 19529728);   //  4,718,592 bf16 wb[t][a][c] (ends 24,248,320)

  k_pre  <<<15488, 256, 0, stream>>>(features, Wf, fTt, (uintT*)wbt);
  k_convm<<<256,   256, 0, stream>>>((const ushortT*)fTt, wbt, bfv, fpj);
  // k_post overlays conv transients -> must run AFTER k_convm
  k_post <<<8127,  256, 0, stream>>>(whh0, wih1, whh1, wgb,
                                     Wst, WstTb, Wout, Woutb,
                                     wih0, Wemb, bih0, bhh0, M0,
                                     st, h1hist, bar);
  k_rec  <<<NWG,   512, 0, stream>>>(gt, M0, wgb, bih1, bhh1, st, h1hist, bar);
  k_att  <<<32*STEPS, 512, 0, stream>>>(features, h1hist, fpj, WstTb, watt,
                                        Woutb, bout, out);
  (void)in_sizes; (void)n_in; (void)out_size; (void)ws_size;
}